// Round 1
// baseline (1202.683 us; speedup 1.0000x reference)
//
#include <hip/hip_runtime.h>

typedef unsigned short u16;
typedef __attribute__((ext_vector_type(8))) short bf16x8;
typedef __attribute__((ext_vector_type(4))) float f32x4;

__device__ inline u16 f2bf(float f) {
  unsigned int u = __float_as_uint(f);
  u += 0x7fffu + ((u >> 16) & 1u);
  return (u16)(u >> 16);
}

__device__ inline uint4 pack8(float4 a, float4 b) {
  uint4 r;
  r.x = (unsigned)f2bf(a.x) | ((unsigned)f2bf(a.y) << 16);
  r.y = (unsigned)f2bf(a.z) | ((unsigned)f2bf(a.w) << 16);
  r.z = (unsigned)f2bf(b.x) | ((unsigned)f2bf(b.y) << 16);
  r.w = (unsigned)f2bf(b.z) | ((unsigned)f2bf(b.w) << 16);
  return r;
}

// dst[c*R + r] = bf16(src[r*C + c])   (transpose + convert, one-time)
__global__ void transpose_bf16_kernel(const float* __restrict__ src,
                                      u16* __restrict__ dst, int R, int C) {
  int t = blockIdx.x * 256 + threadIdx.x;
  if (t < R * C) {
    int r = t / C, c = t - r * C;
    dst[(size_t)c * R + r] = f2bf(src[t]);
  }
}

// stage 128x128 bf16 chunk (rows n, contiguous k) into swizzled LDS
__device__ inline void stage_w_rw(u16* sW, const u16* __restrict__ src,
                                  int roww, int colofs, int tid) {
  int n = tid >> 1, half = tid & 1;
  const u16* s = src + (size_t)n * roww + colofs + half * 64;
#pragma unroll
  for (int q = 0; q < 8; ++q) {
    uint4 v = *(const uint4*)(s + q * 8);
    int byte = n * 256 + ((half * 128 + q * 16) ^ ((n & 7) << 4));
    *(uint4*)((char*)sW + byte) = v;
  }
}

// A (rows 16w..16w+15 of [64][128] swizzled bf16) @ W ([128][128] swizzled, W[n][k]) -> acc[8]
__device__ inline void mfma_pass(const u16* A, const u16* W, f32x4 acc[8],
                                 int w, int lane) {
  const int cA = lane & 15;
  const int ko = (lane >> 4) * 8;
  const int arow = 16 * w + cA;
#pragma unroll
  for (int kk = 0; kk < 4; ++kk) {
    int ka = (kk * 32 + ko) * 2;
    int sx = ka ^ ((cA & 7) << 4);
    bf16x8 a = *(const bf16x8*)((const char*)A + arow * 256 + sx);
#pragma unroll
    for (int nt = 0; nt < 8; ++nt) {
      bf16x8 bb = *(const bf16x8*)((const char*)W + (nt * 16 + cA) * 256 + sx);
      acc[nt] = __builtin_amdgcn_mfma_f32_16x16x32_bf16(a, bb, acc[nt], 0, 0, 0);
    }
  }
}

// relu(acc + bias) -> swizzled bf16 LDS (own wave rows only)
__device__ inline void write_h(u16* sH, const f32x4 acc[8],
                               const float* __restrict__ bias, int w, int lane) {
#pragma unroll
  for (int nt = 0; nt < 8; ++nt) {
    int col = nt * 16 + (lane & 15);
    float bv = bias[col];
#pragma unroll
    for (int i = 0; i < 4; ++i) {
      int rr = 16 * w + ((lane >> 4) * 4) + i;
      float v = fmaxf(acc[nt][i] + bv, 0.f);
      *(u16*)((char*)sH + rr * 256 + ((col * 2) ^ ((rr & 7) << 4))) = f2bf(v);
    }
  }
}

__global__ __launch_bounds__(256) void edge_mlp_kernel(
    const float* __restrict__ ns, const float* __restrict__ ef,
    const int* __restrict__ from_idx, const int* __restrict__ to_idx,
    const u16* __restrict__ Wt1, const u16* __restrict__ Wt2,
    const u16* __restrict__ Wt3, const float* __restrict__ b1,
    const float* __restrict__ b2, const float* __restrict__ b3,
    float* __restrict__ agg, int E) {
  __shared__ u16 sA[64 * 128];
  __shared__ u16 sW[128 * 128];
  __shared__ u16 sH[64 * 128];
  const int tid = threadIdx.x;
  const int lane = tid & 63;
  const int w = tid >> 6;
  const int e0 = blockIdx.x * 64;
  const int dir = blockIdx.y;
  const int* __restrict__ idxA = dir ? to_idx : from_idx;
  const int* __restrict__ idxB = dir ? from_idx : to_idx;

  f32x4 acc[8] = {};
#pragma unroll 1
  for (int kc = 0; kc < 3; ++kc) {
    {  // gather-stage A chunk (64 rows x 128 cols), f32 -> bf16, swizzled
      int row = tid >> 2, seg = tid & 3;
      int e = e0 + row;
      if (e >= E) e = E - 1;
      const float* src;
      if (kc == 0)      src = ns + (size_t)idxA[e] * 128;
      else if (kc == 1) src = ns + (size_t)idxB[e] * 128;
      else              src = ef + (size_t)e * 128;
      const float4* s4 = (const float4*)(src + seg * 32);
#pragma unroll
      for (int q = 0; q < 4; ++q) {
        int byte = row * 256 + ((seg * 64 + q * 16) ^ ((row & 7) << 4));
        *(uint4*)((char*)sA + byte) = pack8(s4[q * 2], s4[q * 2 + 1]);
      }
    }
    stage_w_rw(sW, Wt1, 384, kc * 128, tid);
    __syncthreads();
    mfma_pass(sA, sW, acc, w, lane);
    __syncthreads();
  }
  write_h(sH, acc, b1, w, lane);  // H1
  stage_w_rw(sW, Wt2, 128, 0, tid);
  __syncthreads();
  f32x4 acc2[8] = {};
  mfma_pass(sH, sW, acc2, w, lane);
  write_h(sH, acc2, b2, w, lane);  // H2 (own rows, in-wave ordered after reads)
  __syncthreads();
  stage_w_rw(sW, Wt3, 128, 0, tid);
  __syncthreads();
  f32x4 acc3[8] = {};
  mfma_pass(sH, sW, acc3, w, lane);
  // scatter-add epilogue
#pragma unroll
  for (int nt = 0; nt < 8; ++nt) {
    int col = nt * 16 + (lane & 15);
    float bv = b3[col];
#pragma unroll
    for (int i = 0; i < 4; ++i) {
      int rr = 16 * w + ((lane >> 4) * 4) + i;
      int e = e0 + rr;
      if (e < E) {
        int dest = idxB[e];
        unsafeAtomicAdd(&agg[(size_t)dest * 128 + col], acc3[nt][i] + bv);
      }
    }
  }
}

__global__ __launch_bounds__(256) void gru_kernel(
    const float* __restrict__ x, const float* __restrict__ h,
    const u16* __restrict__ Wt, const u16* __restrict__ Ut,
    const float* __restrict__ b, const float* __restrict__ c,
    float* __restrict__ out, int nrows) {
  __shared__ u16 sX[64 * 128];
  __shared__ u16 sH[64 * 128];
  __shared__ u16 sW[128 * 128];
  const int tid = threadIdx.x;
  const int lane = tid & 63;
  const int w = tid >> 6;
  const int r0 = blockIdx.x * 64;

  {  // stage x and h tiles
    int row = tid >> 2, seg = tid & 3;
    int rr = r0 + row;
    if (rr >= nrows) rr = nrows - 1;
    const float4* sx = (const float4*)(x + (size_t)rr * 128 + seg * 32);
    const float4* sh = (const float4*)(h + (size_t)rr * 128 + seg * 32);
#pragma unroll
    for (int q = 0; q < 4; ++q) {
      int byte = row * 256 + ((seg * 64 + q * 16) ^ ((row & 7) << 4));
      *(uint4*)((char*)sX + byte) = pack8(sx[q * 2], sx[q * 2 + 1]);
      *(uint4*)((char*)sH + byte) = pack8(sh[q * 2], sh[q * 2 + 1]);
    }
  }

  f32x4 ar[8] = {}, az[8] = {}, ai[8] = {}, ah[8] = {};
  // gate r: x@W_r + h@U_r
  stage_w_rw(sW, Wt + 0 * 16384, 128, 0, tid); __syncthreads();
  mfma_pass(sX, sW, ar, w, lane); __syncthreads();
  stage_w_rw(sW, Ut + 0 * 16384, 128, 0, tid); __syncthreads();
  mfma_pass(sH, sW, ar, w, lane); __syncthreads();
  // gate z
  stage_w_rw(sW, Wt + 1 * 16384, 128, 0, tid); __syncthreads();
  mfma_pass(sX, sW, az, w, lane); __syncthreads();
  stage_w_rw(sW, Ut + 1 * 16384, 128, 0, tid); __syncthreads();
  mfma_pass(sH, sW, az, w, lane); __syncthreads();
  // gate n: keep input and hidden parts separate
  stage_w_rw(sW, Wt + 2 * 16384, 128, 0, tid); __syncthreads();
  mfma_pass(sX, sW, ai, w, lane); __syncthreads();
  stage_w_rw(sW, Ut + 2 * 16384, 128, 0, tid); __syncthreads();
  mfma_pass(sH, sW, ah, w, lane);

#pragma unroll
  for (int nt = 0; nt < 8; ++nt) {
    int col = nt * 16 + (lane & 15);
    float brc = b[col] + c[col];
    float bzc = b[128 + col] + c[128 + col];
    float bi = b[256 + col];
    float bc2 = c[256 + col];
#pragma unroll
    for (int i = 0; i < 4; ++i) {
      int rloc = 16 * w + ((lane >> 4) * 4) + i;
      int row = r0 + rloc;
      if (row < nrows) {
        float rg = 1.f / (1.f + __expf(-(ar[nt][i] + brc)));
        float zg = 1.f / (1.f + __expf(-(az[nt][i] + bzc)));
        float pre = ai[nt][i] + bi + rg * (ah[nt][i] + bc2);
        float ng = 2.f / (1.f + __expf(-2.f * pre)) - 1.f;
        float hf = h[(size_t)row * 128 + col];  // exact f32 passthrough
        out[(size_t)row * 128 + col] = (1.f - zg) * ng + zg * hf;
      }
    }
  }
}

extern "C" void kernel_launch(void* const* d_in, const int* in_sizes, int n_in,
                              void* d_out, int out_size, void* d_ws,
                              size_t ws_size, hipStream_t stream) {
  const float* ns = (const float*)d_in[0];
  const float* ef = (const float*)d_in[1];
  const int* from_idx = (const int*)d_in[2];
  const int* to_idx = (const int*)d_in[3];
  const float* mW1 = (const float*)d_in[5];
  const float* mb1 = (const float*)d_in[6];
  const float* mW2 = (const float*)d_in[7];
  const float* mb2 = (const float*)d_in[8];
  const float* mW3 = (const float*)d_in[9];
  const float* mb3 = (const float*)d_in[10];
  const float* gW[3] = {(const float*)d_in[11], (const float*)d_in[15], (const float*)d_in[19]};
  const float* gU[3] = {(const float*)d_in[12], (const float*)d_in[16], (const float*)d_in[20]};
  const float* gb[3] = {(const float*)d_in[13], (const float*)d_in[17], (const float*)d_in[21]};
  const float* gc[3] = {(const float*)d_in[14], (const float*)d_in[18], (const float*)d_in[22]};

  const int N = in_sizes[0] / 128;
  const int E = in_sizes[1] / 128;

  float* agg = (float*)d_ws;  // [N][128] f32
  u16* Wt1 = (u16*)((char*)d_ws + (size_t)N * 128 * 4);  // [128][384]
  u16* Wt2 = Wt1 + 384 * 128;                            // [128][128]
  u16* Wt3 = Wt2 + 128 * 128;                            // [128][128]
  u16* gWt[3], *gUt[3];
  u16* p = Wt3 + 128 * 128;
  for (int i = 0; i < 3; ++i) { gWt[i] = p; p += 384 * 128; gUt[i] = p; p += 384 * 128; }

  // one-time weight transpose + bf16 convert
  auto T = [&](const float* s, u16* d, int R, int C) {
    transpose_bf16_kernel<<<(R * C + 255) / 256, 256, 0, stream>>>(s, d, R, C);
  };
  T(mW1, Wt1, 384, 128);
  T(mW2, Wt2, 128, 128);
  T(mW3, Wt3, 128, 128);
  for (int i = 0; i < 3; ++i) { T(gW[i], gWt[i], 128, 384); T(gU[i], gUt[i], 128, 384); }

  hipMemsetAsync(agg, 0, (size_t)N * 128 * 4, stream);

  dim3 eg((E + 63) / 64, 2);
  edge_mlp_kernel<<<eg, 256, 0, stream>>>(ns, ef, from_idx, to_idx, Wt1, Wt2,
                                          Wt3, mb1, mb2, mb3, agg, E);

  float* h1 = (float*)d_out;  // h1 lives in d_out (overwritten by h3 later)
  float* h2 = agg;            // h2 overwrites agg in-place (row-local)
  int gblocks = (N + 63) / 64;
  gru_kernel<<<gblocks, 256, 0, stream>>>(ns, agg, gWt[0], gUt[0], gb[0], gc[0], h1, N);
  gru_kernel<<<gblocks, 256, 0, stream>>>(agg, h1, gWt[1], gUt[1], gb[1], gc[1], h2, N);
  gru_kernel<<<gblocks, 256, 0, stream>>>(h1, h2, gWt[2], gUt[2], gb[2], gc[2], (float*)d_out, N);
}

// Round 2
// 979.834 us; speedup vs baseline: 1.2274x; 1.2274x over previous
//
#include <hip/hip_runtime.h>

typedef unsigned short u16;
typedef __attribute__((ext_vector_type(8))) short bf16x8;
typedef __attribute__((ext_vector_type(4))) float f32x4;

__device__ inline u16 f2bf(float f) {
  unsigned int u = __float_as_uint(f);
  u += 0x7fffu + ((u >> 16) & 1u);
  return (u16)(u >> 16);
}
__device__ inline float bf2f(u16 v) {
  return __uint_as_float((unsigned)v << 16);
}

__device__ inline uint4 pack8(float4 a, float4 b) {
  uint4 r;
  r.x = (unsigned)f2bf(a.x) | ((unsigned)f2bf(a.y) << 16);
  r.y = (unsigned)f2bf(a.z) | ((unsigned)f2bf(a.w) << 16);
  r.z = (unsigned)f2bf(b.x) | ((unsigned)f2bf(b.y) << 16);
  r.w = (unsigned)f2bf(b.z) | ((unsigned)f2bf(b.w) << 16);
  return r;
}

// dst[c*R + r] = bf16(src[r*C + c])
__global__ void transpose_bf16_kernel(const float* __restrict__ src,
                                      u16* __restrict__ dst, int R, int C) {
  int t = blockIdx.x * 256 + threadIdx.x;
  if (t < R * C) {
    int r = t / C, c = t - r * C;
    dst[(size_t)c * R + r] = f2bf(src[t]);
  }
}

// ---- 256-thread helpers (verified in R1) ----
__device__ inline void stage_w_rw(u16* sW, const u16* __restrict__ src,
                                  int roww, int colofs, int tid) {
  int n = tid >> 1, half = tid & 1;
  const u16* s = src + (size_t)n * roww + colofs + half * 64;
#pragma unroll
  for (int q = 0; q < 8; ++q) {
    uint4 v = *(const uint4*)(s + q * 8);
    int byte = n * 256 + ((half * 128 + q * 16) ^ ((n & 7) << 4));
    *(uint4*)((char*)sW + byte) = v;
  }
}

__device__ inline void mfma_pass(const u16* A, const u16* W, f32x4 acc[8],
                                 int w, int lane) {
  const int cA = lane & 15;
  const int ko = (lane >> 4) * 8;
  const int arow = 16 * w + cA;
#pragma unroll
  for (int kk = 0; kk < 4; ++kk) {
    int ka = (kk * 32 + ko) * 2;
    int sx = ka ^ ((cA & 7) << 4);
    bf16x8 a = *(const bf16x8*)((const char*)A + arow * 256 + sx);
#pragma unroll
    for (int nt = 0; nt < 8; ++nt) {
      bf16x8 bb = *(const bf16x8*)((const char*)W + (nt * 16 + cA) * 256 + sx);
      acc[nt] = __builtin_amdgcn_mfma_f32_16x16x32_bf16(a, bb, acc[nt], 0, 0, 0);
    }
  }
}

// ---- 512-thread weight stage ----
__device__ inline void stage_w_512(u16* sW, const u16* __restrict__ src,
                                   int roww, int colofs, int tid) {
  int n = tid >> 2, quarter = tid & 3;
  const u16* s = src + (size_t)n * roww + colofs + quarter * 32;
#pragma unroll
  for (int q = 0; q < 4; ++q) {
    uint4 v = *(const uint4*)(s + q * 8);
    int byte = n * 256 + ((quarter * 64 + q * 16) ^ ((n & 7) << 4));
    *(uint4*)((char*)sW + byte) = v;
  }
}

// Pa = bf16(ns @ W1a), Pb = bf16(ns @ W1b)
__global__ __launch_bounds__(256) void node_partial_kernel(
    const float* __restrict__ ns, const u16* __restrict__ Wt1,
    u16* __restrict__ Pa, u16* __restrict__ Pb, int N) {
  __shared__ u16 sA[64 * 128];
  __shared__ u16 sW[128 * 128];
  const int tid = threadIdx.x;
  const int lane = tid & 63;
  const int w = tid >> 6;
  const int r0 = blockIdx.x * 64;
  {
    int row = tid >> 2, seg = tid & 3;
    int rr = r0 + row;
    if (rr >= N) rr = N - 1;
    const float4* sx = (const float4*)(ns + (size_t)rr * 128 + seg * 32);
#pragma unroll
    for (int q = 0; q < 4; ++q) {
      int byte = row * 256 + ((seg * 64 + q * 16) ^ ((row & 7) << 4));
      *(uint4*)((char*)sA + byte) = pack8(sx[q * 2], sx[q * 2 + 1]);
    }
  }
  stage_w_rw(sW, Wt1, 384, 0, tid);
  __syncthreads();
  f32x4 accA[8] = {};
  mfma_pass(sA, sW, accA, w, lane);
  __syncthreads();
  stage_w_rw(sW, Wt1, 384, 128, tid);
  __syncthreads();
  f32x4 accB[8] = {};
  mfma_pass(sA, sW, accB, w, lane);
#pragma unroll
  for (int nt = 0; nt < 8; ++nt) {
    int col = nt * 16 + (lane & 15);
#pragma unroll
    for (int i = 0; i < 4; ++i) {
      int rr = 16 * w + ((lane >> 4) * 4) + i;
      int row = r0 + rr;
      if (row < N) {
        Pa[(size_t)row * 128 + col] = f2bf(accA[nt][i]);
        Pb[(size_t)row * 128 + col] = f2bf(accB[nt][i]);
      }
    }
  }
}

// Fused edge MLP: H1 = relu(Pa[src]+Pb[dst]+ef@W1c+b1); H2 = relu(H1@W2+b2);
// out = H2@W3+b3 -> atomic scatter. 128 rows/tile = 64 edges x 2 dirs.
__global__ __launch_bounds__(512, 2) void edge_fused_kernel(
    const float* __restrict__ ef, const int* __restrict__ from_idx,
    const int* __restrict__ to_idx, const u16* __restrict__ Wt1,
    const u16* __restrict__ Wt2, const u16* __restrict__ Wt3,
    const u16* __restrict__ Pa, const u16* __restrict__ Pb,
    const float* __restrict__ b1, const float* __restrict__ b2,
    const float* __restrict__ b3, float* __restrict__ agg, int E, int ntiles) {
  __shared__ u16 sW1c[128 * 128];
  __shared__ u16 sH[128 * 128];
  const int tid = threadIdx.x;
  const int lane = tid & 63;
  const int wv = tid >> 6;      // 0..7
  const int mw = wv >> 1;       // 0..3 (row group of 32)
  const int nw = wv & 1;        // 0..1 (col group of 64)
  const int dir = mw >> 1;      // rows 0-63 dir0, 64-127 dir1
  const int l15 = lane & 15;
  const int lhi = lane >> 4;

  stage_w_512(sW1c, Wt1, 384, 256, tid);

  // per-lane bias fragments
  float b1f[4], b2f[4], b3f[4];
#pragma unroll
  for (int nt = 0; nt < 4; ++nt) {
    int col = (nw << 6) + (nt << 4) + l15;
    b1f[nt] = b1[col];
    b2f[nt] = b2[col];
    b3f[nt] = b3[col];
  }
  // W2/W3 fragments pinned in VGPRs (col = output, k-slice per lane)
  bf16x8 w2f[4][4], w3f[4][4];
#pragma unroll
  for (int nt = 0; nt < 4; ++nt) {
    int c = (nw << 6) + (nt << 4) + l15;
#pragma unroll
    for (int kk = 0; kk < 4; ++kk) {
      w2f[nt][kk] = *(const bf16x8*)(Wt2 + (size_t)c * 128 + (kk << 5) + (lhi << 3));
      w3f[nt][kk] = *(const bf16x8*)(Wt3 + (size_t)c * 128 + (kk << 5) + (lhi << 3));
    }
  }
  __syncthreads();

  for (int t = blockIdx.x; t < ntiles; t += gridDim.x) {
    const int e0 = t << 6;
    // Phase A: ef A-fragments (f32 global -> bf16 regs)
    bf16x8 efA[2][4];
#pragma unroll
    for (int m = 0; m < 2; ++m) {
      int er = ((mw & 1) << 5) + (m << 4) + l15;
      int e = e0 + er;
      if (e >= E) e = E - 1;
      const float* ep = ef + (size_t)e * 128 + (lhi << 3);
#pragma unroll
      for (int kk = 0; kk < 4; ++kk) {
        float4 f0 = *(const float4*)(ep + (kk << 5));
        float4 f1 = *(const float4*)(ep + (kk << 5) + 4);
        uint4 u = pack8(f0, f1);
        efA[m][kk] = *(bf16x8*)&u;
      }
    }
    // Phase B: acc1 = ef @ W1c
    f32x4 acc1[2][4] = {};
#pragma unroll
    for (int kk = 0; kk < 4; ++kk) {
#pragma unroll
      for (int nt = 0; nt < 4; ++nt) {
        int c = (nw << 6) + (nt << 4) + l15;
        int sx = ((kk << 6) + (lhi << 4)) ^ ((c & 7) << 4);
        bf16x8 bb = *(const bf16x8*)((const char*)sW1c + c * 256 + sx);
#pragma unroll
        for (int m = 0; m < 2; ++m)
          acc1[m][nt] = __builtin_amdgcn_mfma_f32_16x16x32_bf16(
              efA[m][kk], bb, acc1[m][nt], 0, 0, 0);
      }
    }
    __syncthreads();  // prev-iter H2 reads done before H1 writes
    // Phase C: H1 = relu(acc1 + Pa[srcA] + Pb[srcB] + b1) -> sH
#pragma unroll
    for (int m = 0; m < 2; ++m) {
#pragma unroll
      for (int i = 0; i < 4; ++i) {
        int er = ((mw & 1) << 5) + (m << 4) + (lhi << 2) + i;
        int e = e0 + er;
        int ec = e < E ? e : E - 1;
        int fi_e = from_idx[ec], ti_e = to_idx[ec];
        int srcA = dir ? ti_e : fi_e;
        int srcB = dir ? fi_e : ti_e;
        int rl = (mw << 5) + (m << 4) + (lhi << 2) + i;
#pragma unroll
        for (int nt = 0; nt < 4; ++nt) {
          int col = (nw << 6) + (nt << 4) + l15;
          float v = acc1[m][nt][i] + b1f[nt] +
                    bf2f(Pa[(size_t)srcA * 128 + col]) +
                    bf2f(Pb[(size_t)srcB * 128 + col]);
          v = fmaxf(v, 0.f);
          *(u16*)((char*)sH + rl * 256 + ((col * 2) ^ ((rl & 7) << 4))) = f2bf(v);
        }
      }
    }
    __syncthreads();
    // Phase D: acc2 = H1 @ W2
    bf16x8 hA[2][4];
#pragma unroll
    for (int m = 0; m < 2; ++m) {
      int ra = (mw << 5) + (m << 4) + l15;
#pragma unroll
      for (int kk = 0; kk < 4; ++kk) {
        int sx = ((kk << 6) + (lhi << 4)) ^ ((ra & 7) << 4);
        hA[m][kk] = *(const bf16x8*)((const char*)sH + ra * 256 + sx);
      }
    }
    f32x4 acc2[2][4] = {};
#pragma unroll
    for (int kk = 0; kk < 4; ++kk)
#pragma unroll
      for (int nt = 0; nt < 4; ++nt)
#pragma unroll
        for (int m = 0; m < 2; ++m)
          acc2[m][nt] = __builtin_amdgcn_mfma_f32_16x16x32_bf16(
              hA[m][kk], w2f[nt][kk], acc2[m][nt], 0, 0, 0);
    __syncthreads();  // all H1 reads done before H2 writes
    // Phase E: H2 = relu(acc2 + b2) -> sH
#pragma unroll
    for (int m = 0; m < 2; ++m) {
#pragma unroll
      for (int i = 0; i < 4; ++i) {
        int rl = (mw << 5) + (m << 4) + (lhi << 2) + i;
#pragma unroll
        for (int nt = 0; nt < 4; ++nt) {
          int col = (nw << 6) + (nt << 4) + l15;
          float v = fmaxf(acc2[m][nt][i] + b2f[nt], 0.f);
          *(u16*)((char*)sH + rl * 256 + ((col * 2) ^ ((rl & 7) << 4))) = f2bf(v);
        }
      }
    }
    __syncthreads();
    // Phase F: acc3 = H2 @ W3
#pragma unroll
    for (int m = 0; m < 2; ++m) {
      int ra = (mw << 5) + (m << 4) + l15;
#pragma unroll
      for (int kk = 0; kk < 4; ++kk) {
        int sx = ((kk << 6) + (lhi << 4)) ^ ((ra & 7) << 4);
        hA[m][kk] = *(const bf16x8*)((const char*)sH + ra * 256 + sx);
      }
    }
    f32x4 acc3[2][4] = {};
#pragma unroll
    for (int kk = 0; kk < 4; ++kk)
#pragma unroll
      for (int nt = 0; nt < 4; ++nt)
#pragma unroll
        for (int m = 0; m < 2; ++m)
          acc3[m][nt] = __builtin_amdgcn_mfma_f32_16x16x32_bf16(
              hA[m][kk], w3f[nt][kk], acc3[m][nt], 0, 0, 0);
    // Phase G: scatter-add
#pragma unroll
    for (int m = 0; m < 2; ++m) {
#pragma unroll
      for (int i = 0; i < 4; ++i) {
        int er = ((mw & 1) << 5) + (m << 4) + (lhi << 2) + i;
        int e = e0 + er;
        if (e < E) {
          int fi_e = from_idx[e], ti_e = to_idx[e];
          int dest = dir ? fi_e : ti_e;
#pragma unroll
          for (int nt = 0; nt < 4; ++nt) {
            int col = (nw << 6) + (nt << 4) + l15;
            unsafeAtomicAdd(&agg[(size_t)dest * 128 + col],
                            acc3[m][nt][i] + b3f[nt]);
          }
        }
      }
    }
  }
}

__global__ __launch_bounds__(256) void gru_kernel(
    const float* __restrict__ x, const float* __restrict__ h,
    const u16* __restrict__ Wt, const u16* __restrict__ Ut,
    const float* __restrict__ b, const float* __restrict__ c,
    float* __restrict__ out, int nrows) {
  __shared__ u16 sX[64 * 128];
  __shared__ u16 sH[64 * 128];
  __shared__ u16 sW[128 * 128];
  const int tid = threadIdx.x;
  const int lane = tid & 63;
  const int w = tid >> 6;
  const int r0 = blockIdx.x * 64;
  {
    int row = tid >> 2, seg = tid & 3;
    int rr = r0 + row;
    if (rr >= nrows) rr = nrows - 1;
    const float4* sx = (const float4*)(x + (size_t)rr * 128 + seg * 32);
    const float4* sh = (const float4*)(h + (size_t)rr * 128 + seg * 32);
#pragma unroll
    for (int q = 0; q < 4; ++q) {
      int byte = row * 256 + ((seg * 64 + q * 16) ^ ((row & 7) << 4));
      *(uint4*)((char*)sX + byte) = pack8(sx[q * 2], sx[q * 2 + 1]);
      *(uint4*)((char*)sH + byte) = pack8(sh[q * 2], sh[q * 2 + 1]);
    }
  }
  f32x4 ar[8] = {}, az[8] = {}, ai[8] = {}, ah[8] = {};
  stage_w_rw(sW, Wt + 0 * 16384, 128, 0, tid); __syncthreads();
  mfma_pass(sX, sW, ar, w, lane); __syncthreads();
  stage_w_rw(sW, Ut + 0 * 16384, 128, 0, tid); __syncthreads();
  mfma_pass(sH, sW, ar, w, lane); __syncthreads();
  stage_w_rw(sW, Wt + 1 * 16384, 128, 0, tid); __syncthreads();
  mfma_pass(sX, sW, az, w, lane); __syncthreads();
  stage_w_rw(sW, Ut + 1 * 16384, 128, 0, tid); __syncthreads();
  mfma_pass(sH, sW, az, w, lane); __syncthreads();
  stage_w_rw(sW, Wt + 2 * 16384, 128, 0, tid); __syncthreads();
  mfma_pass(sX, sW, ai, w, lane); __syncthreads();
  stage_w_rw(sW, Ut + 2 * 16384, 128, 0, tid); __syncthreads();
  mfma_pass(sH, sW, ah, w, lane);
#pragma unroll
  for (int nt = 0; nt < 8; ++nt) {
    int col = nt * 16 + (lane & 15);
    float brc = b[col] + c[col];
    float bzc = b[128 + col] + c[128 + col];
    float bi = b[256 + col];
    float bc2 = c[256 + col];
#pragma unroll
    for (int i = 0; i < 4; ++i) {
      int rloc = 16 * w + ((lane >> 4) * 4) + i;
      int row = r0 + rloc;
      if (row < nrows) {
        float rg = 1.f / (1.f + __expf(-(ar[nt][i] + brc)));
        float zg = 1.f / (1.f + __expf(-(az[nt][i] + bzc)));
        float pre = ai[nt][i] + bi + rg * (ah[nt][i] + bc2);
        float ng = 2.f / (1.f + __expf(-2.f * pre)) - 1.f;
        float hf = h[(size_t)row * 128 + col];
        out[(size_t)row * 128 + col] = (1.f - zg) * ng + zg * hf;
      }
    }
  }
}

extern "C" void kernel_launch(void* const* d_in, const int* in_sizes, int n_in,
                              void* d_out, int out_size, void* d_ws,
                              size_t ws_size, hipStream_t stream) {
  const float* ns = (const float*)d_in[0];
  const float* ef = (const float*)d_in[1];
  const int* from_idx = (const int*)d_in[2];
  const int* to_idx = (const int*)d_in[3];
  const float* mW1 = (const float*)d_in[5];
  const float* mb1 = (const float*)d_in[6];
  const float* mW2 = (const float*)d_in[7];
  const float* mb2 = (const float*)d_in[8];
  const float* mW3 = (const float*)d_in[9];
  const float* mb3 = (const float*)d_in[10];
  const float* gW[3] = {(const float*)d_in[11], (const float*)d_in[15], (const float*)d_in[19]};
  const float* gU[3] = {(const float*)d_in[12], (const float*)d_in[16], (const float*)d_in[20]};
  const float* gb[3] = {(const float*)d_in[13], (const float*)d_in[17], (const float*)d_in[21]};
  const float* gc[3] = {(const float*)d_in[14], (const float*)d_in[18], (const float*)d_in[22]};

  const int N = in_sizes[0] / 128;
  const int E = in_sizes[1] / 128;

  float* agg = (float*)d_ws;                              // [N][128] f32
  u16* Pa = (u16*)((char*)d_ws + (size_t)N * 128 * 4);    // [N][128] bf16
  u16* Pb = Pa + (size_t)N * 128;
  u16* Wt1 = Pb + (size_t)N * 128;  // [128][384]
  u16* Wt2 = Wt1 + 384 * 128;       // [128][128]
  u16* Wt3 = Wt2 + 128 * 128;
  u16* gWt[3], *gUt[3];
  u16* p = Wt3 + 128 * 128;
  for (int i = 0; i < 3; ++i) { gWt[i] = p; p += 384 * 128; gUt[i] = p; p += 384 * 128; }

  auto T = [&](const float* s, u16* d, int R, int C) {
    transpose_bf16_kernel<<<(R * C + 255) / 256, 256, 0, stream>>>(s, d, R, C);
  };
  T(mW1, Wt1, 384, 128);
  T(mW2, Wt2, 128, 128);
  T(mW3, Wt3, 128, 128);
  for (int i = 0; i < 3; ++i) { T(gW[i], gWt[i], 128, 384); T(gU[i], gUt[i], 128, 384); }

  hipMemsetAsync(agg, 0, (size_t)N * 128 * 4, stream);

  node_partial_kernel<<<(N + 63) / 64, 256, 0, stream>>>(ns, Wt1, Pa, Pb, N);

  int ntiles = (E + 63) / 64;
  int egrid = ntiles < 1024 ? ntiles : 1024;
  edge_fused_kernel<<<egrid, 512, 0, stream>>>(ef, from_idx, to_idx, Wt1, Wt2,
                                               Wt3, Pa, Pb, mb1, mb2, mb3, agg,
                                               E, ntiles);

  float* h1 = (float*)d_out;
  float* h2 = agg;
  int gblocks = (N + 63) / 64;
  gru_kernel<<<gblocks, 256, 0, stream>>>(ns, agg, gWt[0], gUt[0], gb[0], gc[0], h1, N);
  gru_kernel<<<gblocks, 256, 0, stream>>>(agg, h1, gWt[1], gUt[1], gb[1], gc[1], h2, N);
  gru_kernel<<<gblocks, 256, 0, stream>>>(h1, h2, gWt[2], gUt[2], gb[2], gc[2], (float*)d_out, N);
}

// Round 3
// 915.804 us; speedup vs baseline: 1.3133x; 1.0699x over previous
//
#include <hip/hip_runtime.h>

typedef unsigned short u16;
typedef __attribute__((ext_vector_type(8))) short bf16x8;
typedef __attribute__((ext_vector_type(4))) float f32x4;

__device__ inline u16 f2bf(float f) {
  unsigned int u = __float_as_uint(f);
  u += 0x7fffu + ((u >> 16) & 1u);
  return (u16)(u >> 16);
}
__device__ inline float bf2f(u16 v) {
  return __uint_as_float((unsigned)v << 16);
}

__device__ inline uint4 pack8(float4 a, float4 b) {
  uint4 r;
  r.x = (unsigned)f2bf(a.x) | ((unsigned)f2bf(a.y) << 16);
  r.y = (unsigned)f2bf(a.z) | ((unsigned)f2bf(a.w) << 16);
  r.z = (unsigned)f2bf(b.x) | ((unsigned)f2bf(b.y) << 16);
  r.w = (unsigned)f2bf(b.z) | ((unsigned)f2bf(b.w) << 16);
  return r;
}

// packed bf16x2 atomic add (fire-and-forget)
__device__ inline void atomic_pk_add_bf16(u16* p, unsigned v) {
  asm volatile("global_atomic_pk_add_bf16 %0, %1, off" : : "v"(p), "v"(v)
               : "memory");
}

// dst[c*R + r] = bf16(src[r*C + c])
__global__ void transpose_bf16_kernel(const float* __restrict__ src,
                                      u16* __restrict__ dst, int R, int C) {
  int t = blockIdx.x * 256 + threadIdx.x;
  if (t < R * C) {
    int r = t / C, c = t - r * C;
    dst[(size_t)c * R + r] = f2bf(src[t]);
  }
}

__global__ void bf16_to_f32_kernel(const u16* __restrict__ in,
                                   float* __restrict__ out, int n8) {
  int t = blockIdx.x * 256 + threadIdx.x;
  if (t < n8) {
    uint4 v = ((const uint4*)in)[t];
    u16* p = (u16*)&v;
    float4 o0 = {bf2f(p[0]), bf2f(p[1]), bf2f(p[2]), bf2f(p[3])};
    float4 o1 = {bf2f(p[4]), bf2f(p[5]), bf2f(p[6]), bf2f(p[7])};
    ((float4*)out)[t * 2] = o0;
    ((float4*)out)[t * 2 + 1] = o1;
  }
}

// ---- 256-thread helpers (verified R1/R2) ----
__device__ inline void stage_w_rw(u16* sW, const u16* __restrict__ src,
                                  int roww, int colofs, int tid) {
  int n = tid >> 1, half = tid & 1;
  const u16* s = src + (size_t)n * roww + colofs + half * 64;
#pragma unroll
  for (int q = 0; q < 8; ++q) {
    uint4 v = *(const uint4*)(s + q * 8);
    int byte = n * 256 + ((half * 128 + q * 16) ^ ((n & 7) << 4));
    *(uint4*)((char*)sW + byte) = v;
  }
}

__device__ inline void mfma_pass(const u16* A, const u16* W, f32x4 acc[8],
                                 int w, int lane) {
  const int cA = lane & 15;
  const int ko = (lane >> 4) * 8;
  const int arow = 16 * w + cA;
#pragma unroll
  for (int kk = 0; kk < 4; ++kk) {
    int ka = (kk * 32 + ko) * 2;
    int sx = ka ^ ((cA & 7) << 4);
    bf16x8 a = *(const bf16x8*)((const char*)A + arow * 256 + sx);
#pragma unroll
    for (int nt = 0; nt < 8; ++nt) {
      bf16x8 bb = *(const bf16x8*)((const char*)W + (nt * 16 + cA) * 256 + sx);
      acc[nt] = __builtin_amdgcn_mfma_f32_16x16x32_bf16(a, bb, acc[nt], 0, 0, 0);
    }
  }
}

// ---- 512-thread weight stage ----
__device__ inline void stage_w_512(u16* sW, const u16* __restrict__ src,
                                   int roww, int colofs, int tid) {
  int n = tid >> 2, quarter = tid & 3;
  const u16* s = src + (size_t)n * roww + colofs + quarter * 32;
#pragma unroll
  for (int q = 0; q < 4; ++q) {
    uint4 v = *(const uint4*)(s + q * 8);
    int byte = n * 256 + ((quarter * 64 + q * 16) ^ ((n & 7) << 4));
    *(uint4*)((char*)sW + byte) = v;
  }
}

// Pa = bf16(ns @ W1a), Pb = bf16(ns @ W1b)
__global__ __launch_bounds__(256) void node_partial_kernel(
    const float* __restrict__ ns, const u16* __restrict__ Wt1,
    u16* __restrict__ Pa, u16* __restrict__ Pb, int N) {
  __shared__ u16 sA[64 * 128];
  __shared__ u16 sW[128 * 128];
  const int tid = threadIdx.x;
  const int lane = tid & 63;
  const int w = tid >> 6;
  const int r0 = blockIdx.x * 64;
  {
    int row = tid >> 2, seg = tid & 3;
    int rr = r0 + row;
    if (rr >= N) rr = N - 1;
    const float4* sx = (const float4*)(ns + (size_t)rr * 128 + seg * 32);
#pragma unroll
    for (int q = 0; q < 4; ++q) {
      int byte = row * 256 + ((seg * 64 + q * 16) ^ ((row & 7) << 4));
      *(uint4*)((char*)sA + byte) = pack8(sx[q * 2], sx[q * 2 + 1]);
    }
  }
  stage_w_rw(sW, Wt1, 384, 0, tid);
  __syncthreads();
  f32x4 accA[8] = {};
  mfma_pass(sA, sW, accA, w, lane);
  __syncthreads();
  stage_w_rw(sW, Wt1, 384, 128, tid);
  __syncthreads();
  f32x4 accB[8] = {};
  mfma_pass(sA, sW, accB, w, lane);
#pragma unroll
  for (int nt = 0; nt < 8; ++nt) {
    int col = nt * 16 + (lane & 15);
#pragma unroll
    for (int i = 0; i < 4; ++i) {
      int rr = 16 * w + ((lane >> 4) * 4) + i;
      int row = r0 + rr;
      if (row < N) {
        Pa[(size_t)row * 128 + col] = f2bf(accA[nt][i]);
        Pb[(size_t)row * 128 + col] = f2bf(accB[nt][i]);
      }
    }
  }
}

// Fused edge MLP, 64 edges/tile, both directions (128 H1 rows).
// sEF = ef@W1c+b1 computed once, shared by both dirs.
__global__ __launch_bounds__(512, 2) void edge_fused_kernel(
    const float* __restrict__ ef, const int* __restrict__ from_idx,
    const int* __restrict__ to_idx, const u16* __restrict__ Wt1,
    const u16* __restrict__ Wt2, const u16* __restrict__ Wt3,
    const u16* __restrict__ Pa, const u16* __restrict__ Pb,
    const float* __restrict__ b1, const float* __restrict__ b2,
    const float* __restrict__ b3, u16* __restrict__ aggb, int E, int ntiles) {
  __shared__ u16 sW1c[128 * 128];  // 32 KB
  __shared__ u16 sH[128 * 128];    // 32 KB
  __shared__ u16 sEF[64 * 128];    // 16 KB  -> 80 KB total, 2 blocks/CU
  const int tid = threadIdx.x;
  const int lane = tid & 63;
  const int wv = tid >> 6;      // 0..7
  const int mw = wv >> 1;       // 0..3
  const int nw = wv & 1;        // 0..1
  const int dir = mw >> 1;      // 0 or 1
  const int l15 = lane & 15;
  const int lhi = lane >> 4;

  stage_w_512(sW1c, Wt1, 384, 256, tid);

  float b1f[4], b2f[4], b3f[4];
#pragma unroll
  for (int nt = 0; nt < 4; ++nt) {
    int col = (nw << 6) + (nt << 4) + l15;
    b1f[nt] = b1[col];
    b2f[nt] = b2[col];
    b3f[nt] = b3[col];
  }
  bf16x8 w2f[4][4], w3f[4][4];
#pragma unroll
  for (int nt = 0; nt < 4; ++nt) {
    int c = (nw << 6) + (nt << 4) + l15;
#pragma unroll
    for (int kk = 0; kk < 4; ++kk) {
      w2f[nt][kk] = *(const bf16x8*)(Wt2 + (size_t)c * 128 + (kk << 5) + (lhi << 3));
      w3f[nt][kk] = *(const bf16x8*)(Wt3 + (size_t)c * 128 + (kk << 5) + (lhi << 3));
    }
  }
  __syncthreads();

  for (int t = blockIdx.x; t < ntiles; t += gridDim.x) {
    const int e0 = t << 6;
    // Phase A: sEF = ef@W1c + b1  (64x128, computed once for both dirs)
    {
      const int arow = (mw << 4) + l15;  // 0..63
      int e = e0 + arow;
      if (e >= E) e = E - 1;
      const float* ep = ef + (size_t)e * 128 + (lhi << 3);
      bf16x8 efA[4];
#pragma unroll
      for (int kk = 0; kk < 4; ++kk) {
        float4 f0 = *(const float4*)(ep + (kk << 5));
        float4 f1 = *(const float4*)(ep + (kk << 5) + 4);
        uint4 u = pack8(f0, f1);
        efA[kk] = *(bf16x8*)&u;
      }
      f32x4 a1[4] = {};
#pragma unroll
      for (int kk = 0; kk < 4; ++kk) {
#pragma unroll
        for (int nt = 0; nt < 4; ++nt) {
          int c = (nw << 6) + (nt << 4) + l15;
          int sx = ((kk << 6) + (lhi << 4)) ^ ((c & 7) << 4);
          bf16x8 bb = *(const bf16x8*)((const char*)sW1c + c * 256 + sx);
          a1[nt] = __builtin_amdgcn_mfma_f32_16x16x32_bf16(efA[kk], bb, a1[nt], 0, 0, 0);
        }
      }
#pragma unroll
      for (int nt = 0; nt < 4; ++nt) {
        int col = (nw << 6) + (nt << 4) + l15;
#pragma unroll
        for (int i = 0; i < 4; ++i) {
          int row = (mw << 4) + (lhi << 2) + i;
          *(u16*)((char*)sEF + row * 256 + ((col * 2) ^ ((row & 7) << 4))) =
              f2bf(a1[nt][i] + b1f[nt]);
        }
      }
    }
    __syncthreads();
    // Phase C: H1 = relu(sEF + Pa[srcA] + Pb[srcB]) -> sH, vectorized gathers
#pragma unroll
    for (int it = 0; it < 4; ++it) {
      int row = (tid >> 4) + (it << 5);   // 0..127
      int c8 = tid & 15;                  // 16B chunk
      int er = row & 63, d = row >> 6;
      int ec = e0 + er;
      if (ec >= E) ec = E - 1;
      int fi_e = from_idx[ec], ti_e = to_idx[ec];
      int sA = d ? ti_e : fi_e;
      int sB = d ? fi_e : ti_e;
      uint4 efv = *(const uint4*)((const char*)sEF + er * 256 + ((c8 << 4) ^ ((er & 7) << 4)));
      uint4 pav = *(const uint4*)(Pa + (size_t)sA * 128 + (c8 << 3));
      uint4 pbv = *(const uint4*)(Pb + (size_t)sB * 128 + (c8 << 3));
      const u16* pe = (const u16*)&efv;
      const u16* pa = (const u16*)&pav;
      const u16* pb = (const u16*)&pbv;
      unsigned o[4];
#pragma unroll
      for (int j = 0; j < 4; ++j) {
        float v0 = fmaxf(bf2f(pe[2 * j]) + bf2f(pa[2 * j]) + bf2f(pb[2 * j]), 0.f);
        float v1 = fmaxf(bf2f(pe[2 * j + 1]) + bf2f(pa[2 * j + 1]) + bf2f(pb[2 * j + 1]), 0.f);
        o[j] = (unsigned)f2bf(v0) | ((unsigned)f2bf(v1) << 16);
      }
      *(uint4*)((char*)sH + row * 256 + ((c8 << 4) ^ ((row & 7) << 4))) = *(uint4*)o;
    }
    __syncthreads();
    // Phase D: acc2 = H1 @ W2
    bf16x8 hA[2][4];
#pragma unroll
    for (int m = 0; m < 2; ++m) {
      int ra = (mw << 5) + (m << 4) + l15;
#pragma unroll
      for (int kk = 0; kk < 4; ++kk) {
        int sx = ((kk << 6) + (lhi << 4)) ^ ((ra & 7) << 4);
        hA[m][kk] = *(const bf16x8*)((const char*)sH + ra * 256 + sx);
      }
    }
    f32x4 acc2[2][4] = {};
#pragma unroll
    for (int kk = 0; kk < 4; ++kk)
#pragma unroll
      for (int nt = 0; nt < 4; ++nt)
#pragma unroll
        for (int m = 0; m < 2; ++m)
          acc2[m][nt] = __builtin_amdgcn_mfma_f32_16x16x32_bf16(
              hA[m][kk], w2f[nt][kk], acc2[m][nt], 0, 0, 0);
    __syncthreads();
    // Phase E: H2 = relu(acc2 + b2) -> sH
#pragma unroll
    for (int m = 0; m < 2; ++m) {
#pragma unroll
      for (int i = 0; i < 4; ++i) {
        int rl = (mw << 5) + (m << 4) + (lhi << 2) + i;
#pragma unroll
        for (int nt = 0; nt < 4; ++nt) {
          int col = (nw << 6) + (nt << 4) + l15;
          float v = fmaxf(acc2[m][nt][i] + b2f[nt], 0.f);
          *(u16*)((char*)sH + rl * 256 + ((col * 2) ^ ((rl & 7) << 4))) = f2bf(v);
        }
      }
    }
    __syncthreads();
    // Phase F: acc3 = H2 @ W3
#pragma unroll
    for (int m = 0; m < 2; ++m) {
      int ra = (mw << 5) + (m << 4) + l15;
#pragma unroll
      for (int kk = 0; kk < 4; ++kk) {
        int sx = ((kk << 6) + (lhi << 4)) ^ ((ra & 7) << 4);
        hA[m][kk] = *(const bf16x8*)((const char*)sH + ra * 256 + sx);
      }
    }
    f32x4 acc3[2][4] = {};
#pragma unroll
    for (int kk = 0; kk < 4; ++kk)
#pragma unroll
      for (int nt = 0; nt < 4; ++nt)
#pragma unroll
        for (int m = 0; m < 2; ++m)
          acc3[m][nt] = __builtin_amdgcn_mfma_f32_16x16x32_bf16(
              hA[m][kk], w3f[nt][kk], acc3[m][nt], 0, 0, 0);
    // Phase G: packed-bf16 atomic scatter (even lanes carry col pairs)
#pragma unroll
    for (int m = 0; m < 2; ++m) {
#pragma unroll
      for (int i = 0; i < 4; ++i) {
        int er = ((mw & 1) << 5) + (m << 4) + (lhi << 2) + i;
        int e = e0 + er;
#pragma unroll
        for (int nt = 0; nt < 4; ++nt) {
          int col = (nw << 6) + (nt << 4) + l15;
          float v = acc3[m][nt][i] + b3f[nt];
          float vp = __shfl_xor(v, 1);
          if (e < E && !(lane & 1)) {
            int dest = dir ? from_idx[e] : to_idx[e];
            unsigned d2 = (unsigned)f2bf(v) | ((unsigned)f2bf(vp) << 16);
            atomic_pk_add_bf16(aggb + (size_t)dest * 128 + col, d2);
          }
        }
      }
    }
  }
}

__global__ __launch_bounds__(256) void gru_kernel(
    const float* __restrict__ x, const float* __restrict__ h,
    const u16* __restrict__ Wt, const u16* __restrict__ Ut,
    const float* __restrict__ b, const float* __restrict__ c,
    float* __restrict__ out, int nrows) {
  __shared__ u16 sX[64 * 128];
  __shared__ u16 sH[64 * 128];
  __shared__ u16 sW[128 * 128];
  const int tid = threadIdx.x;
  const int lane = tid & 63;
  const int w = tid >> 6;
  const int r0 = blockIdx.x * 64;
  {
    int row = tid >> 2, seg = tid & 3;
    int rr = r0 + row;
    if (rr >= nrows) rr = nrows - 1;
    const float4* sx = (const float4*)(x + (size_t)rr * 128 + seg * 32);
    const float4* sh = (const float4*)(h + (size_t)rr * 128 + seg * 32);
#pragma unroll
    for (int q = 0; q < 4; ++q) {
      int byte = row * 256 + ((seg * 64 + q * 16) ^ ((row & 7) << 4));
      *(uint4*)((char*)sX + byte) = pack8(sx[q * 2], sx[q * 2 + 1]);
      *(uint4*)((char*)sH + byte) = pack8(sh[q * 2], sh[q * 2 + 1]);
    }
  }
  f32x4 ar[8] = {}, az[8] = {}, ai[8] = {}, ah[8] = {};
  stage_w_rw(sW, Wt + 0 * 16384, 128, 0, tid); __syncthreads();
  mfma_pass(sX, sW, ar, w, lane); __syncthreads();
  stage_w_rw(sW, Ut + 0 * 16384, 128, 0, tid); __syncthreads();
  mfma_pass(sH, sW, ar, w, lane); __syncthreads();
  stage_w_rw(sW, Wt + 1 * 16384, 128, 0, tid); __syncthreads();
  mfma_pass(sX, sW, az, w, lane); __syncthreads();
  stage_w_rw(sW, Ut + 1 * 16384, 128, 0, tid); __syncthreads();
  mfma_pass(sH, sW, az, w, lane); __syncthreads();
  stage_w_rw(sW, Wt + 2 * 16384, 128, 0, tid); __syncthreads();
  mfma_pass(sX, sW, ai, w, lane); __syncthreads();
  stage_w_rw(sW, Ut + 2 * 16384, 128, 0, tid); __syncthreads();
  mfma_pass(sH, sW, ah, w, lane);
#pragma unroll
  for (int nt = 0; nt < 8; ++nt) {
    int col = nt * 16 + (lane & 15);
    float brc = b[col] + c[col];
    float bzc = b[128 + col] + c[128 + col];
    float bi = b[256 + col];
    float bc2 = c[256 + col];
#pragma unroll
    for (int i = 0; i < 4; ++i) {
      int rloc = 16 * w + ((lane >> 4) * 4) + i;
      int row = r0 + rloc;
      if (row < nrows) {
        float rg = 1.f / (1.f + __expf(-(ar[nt][i] + brc)));
        float zg = 1.f / (1.f + __expf(-(az[nt][i] + bzc)));
        float pre = ai[nt][i] + bi + rg * (ah[nt][i] + bc2);
        float ng = 2.f / (1.f + __expf(-2.f * pre)) - 1.f;
        float hf = h[(size_t)row * 128 + col];
        out[(size_t)row * 128 + col] = (1.f - zg) * ng + zg * hf;
      }
    }
  }
}

extern "C" void kernel_launch(void* const* d_in, const int* in_sizes, int n_in,
                              void* d_out, int out_size, void* d_ws,
                              size_t ws_size, hipStream_t stream) {
  const float* ns = (const float*)d_in[0];
  const float* ef = (const float*)d_in[1];
  const int* from_idx = (const int*)d_in[2];
  const int* to_idx = (const int*)d_in[3];
  const float* mW1 = (const float*)d_in[5];
  const float* mb1 = (const float*)d_in[6];
  const float* mW2 = (const float*)d_in[7];
  const float* mb2 = (const float*)d_in[8];
  const float* mW3 = (const float*)d_in[9];
  const float* mb3 = (const float*)d_in[10];
  const float* gW[3] = {(const float*)d_in[11], (const float*)d_in[15], (const float*)d_in[19]};
  const float* gU[3] = {(const float*)d_in[12], (const float*)d_in[16], (const float*)d_in[20]};
  const float* gb[3] = {(const float*)d_in[13], (const float*)d_in[17], (const float*)d_in[21]};
  const float* gc[3] = {(const float*)d_in[14], (const float*)d_in[18], (const float*)d_in[22]};

  const int N = in_sizes[0] / 128;
  const int E = in_sizes[1] / 128;

  u16* aggb = (u16*)d_ws;                                   // [N][128] bf16
  float* aggf = (float*)((char*)d_ws + (size_t)N * 128 * 2);// [N][128] f32
  u16* Pa = (u16*)((char*)aggf + (size_t)N * 128 * 4);      // [N][128] bf16
  u16* Pb = Pa + (size_t)N * 128;
  u16* Wt1 = Pb + (size_t)N * 128;  // [128][384]
  u16* Wt2 = Wt1 + 384 * 128;       // [128][128]
  u16* Wt3 = Wt2 + 128 * 128;
  u16* gWt[3], *gUt[3];
  u16* p = Wt3 + 128 * 128;
  for (int i = 0; i < 3; ++i) { gWt[i] = p; p += 384 * 128; gUt[i] = p; p += 384 * 128; }

  auto T = [&](const float* s, u16* d, int R, int C) {
    transpose_bf16_kernel<<<(R * C + 255) / 256, 256, 0, stream>>>(s, d, R, C);
  };
  T(mW1, Wt1, 384, 128);
  T(mW2, Wt2, 128, 128);
  T(mW3, Wt3, 128, 128);
  for (int i = 0; i < 3; ++i) { T(gW[i], gWt[i], 128, 384); T(gU[i], gUt[i], 128, 384); }

  hipMemsetAsync(aggb, 0, (size_t)N * 128 * 2, stream);

  node_partial_kernel<<<(N + 63) / 64, 256, 0, stream>>>(ns, Wt1, Pa, Pb, N);

  int ntiles = (E + 63) / 64;
  int egrid = ntiles < 512 ? ntiles : 512;
  edge_fused_kernel<<<egrid, 512, 0, stream>>>(ef, from_idx, to_idx, Wt1, Wt2,
                                               Wt3, Pa, Pb, mb1, mb2, mb3,
                                               aggb, E, ntiles);

  bf16_to_f32_kernel<<<(N * 16 + 255) / 256, 256, 0, stream>>>(aggb, aggf, N * 16);

  float* h1 = (float*)d_out;
  float* h2 = aggf;
  int gblocks = (N + 63) / 64;
  gru_kernel<<<gblocks, 256, 0, stream>>>(ns, aggf, gWt[0], gUt[0], gb[0], gc[0], h1, N);
  gru_kernel<<<gblocks, 256, 0, stream>>>(aggf, h1, gWt[1], gUt[1], gb[1], gc[1], h2, N);
  gru_kernel<<<gblocks, 256, 0, stream>>>(h1, h2, gWt[2], gUt[2], gb[2], gc[2], (float*)d_out, N);
}

// Round 4
// 756.036 us; speedup vs baseline: 1.5908x; 1.2113x over previous
//
#include <hip/hip_runtime.h>

typedef unsigned short u16;
typedef __attribute__((ext_vector_type(8))) short bf16x8;
typedef __attribute__((ext_vector_type(4))) float f32x4;

__device__ inline u16 f2bf(float f) {
  unsigned int u = __float_as_uint(f);
  u += 0x7fffu + ((u >> 16) & 1u);
  return (u16)(u >> 16);
}
__device__ inline float bf2f(u16 v) {
  return __uint_as_float((unsigned)v << 16);
}

__device__ inline uint4 pack8(float4 a, float4 b) {
  uint4 r;
  r.x = (unsigned)f2bf(a.x) | ((unsigned)f2bf(a.y) << 16);
  r.y = (unsigned)f2bf(a.z) | ((unsigned)f2bf(a.w) << 16);
  r.z = (unsigned)f2bf(b.x) | ((unsigned)f2bf(b.y) << 16);
  r.w = (unsigned)f2bf(b.z) | ((unsigned)f2bf(b.w) << 16);
  return r;
}

__device__ inline void atomic_pk_add_bf16(u16* p, unsigned v) {
  asm volatile("global_atomic_pk_add_bf16 %0, %1, off" : : "v"(p), "v"(v)
               : "memory");
}

// dst[c*R + r] = bf16(src[r*C + c])
__global__ void transpose_bf16_kernel(const float* __restrict__ src,
                                      u16* __restrict__ dst, int R, int C) {
  int t = blockIdx.x * 256 + threadIdx.x;
  if (t < R * C) {
    int r = t / C, c = t - r * C;
    dst[(size_t)c * R + r] = f2bf(src[t]);
  }
}

__global__ void bf16_to_f32_kernel(const u16* __restrict__ in,
                                   float* __restrict__ out, int n8) {
  int t = blockIdx.x * 256 + threadIdx.x;
  if (t < n8) {
    uint4 v = ((const uint4*)in)[t];
    u16* p = (u16*)&v;
    float4 o0 = {bf2f(p[0]), bf2f(p[1]), bf2f(p[2]), bf2f(p[3])};
    float4 o1 = {bf2f(p[4]), bf2f(p[5]), bf2f(p[6]), bf2f(p[7])};
    ((float4*)out)[t * 2] = o0;
    ((float4*)out)[t * 2 + 1] = o1;
  }
}

// ---------------- CSR build ----------------
__global__ void count_kernel(const int* __restrict__ fi,
                             const int* __restrict__ ti,
                             int* __restrict__ cnt, int E) {
  int e = blockIdx.x * 256 + threadIdx.x;
  if (e < E) {
    atomicAdd(&cnt[ti[e]], 1);
    atomicAdd(&cnt[fi[e]], 1);
  }
}

__global__ void scan1_kernel(const int* __restrict__ cnt,
                             int* __restrict__ partial, int N, int chunk) {
  __shared__ int sdata[256];
  int b = blockIdx.x, t = threadIdx.x;
  int base = b * chunk;
  int sum = 0;
  for (int i = t; i < chunk; i += 256) {
    int idx = base + i;
    if (idx < N) sum += cnt[idx];
  }
  sdata[t] = sum;
  __syncthreads();
  for (int s2 = 128; s2 > 0; s2 >>= 1) {
    if (t < s2) sdata[t] += sdata[t + s2];
    __syncthreads();
  }
  if (t == 0) partial[b] = sdata[0];
}

__global__ void scan2_kernel(int* __restrict__ partial, int* __restrict__ off,
                             int N) {
  __shared__ int s[256];
  int t = threadIdx.x;
  int own = partial[t];
  s[t] = own;
  __syncthreads();
  for (int d2 = 1; d2 < 256; d2 <<= 1) {
    int v = (t >= d2) ? s[t - d2] : 0;
    __syncthreads();
    s[t] += v;
    __syncthreads();
  }
  partial[t] = s[t] - own;           // exclusive
  if (t == 255) off[N] = s[255];     // total = 2E
}

__global__ void scan3_kernel(const int* __restrict__ cnt,
                             const int* __restrict__ partialEx,
                             int* __restrict__ off, int* __restrict__ cursor,
                             int N, int chunk) {
  __shared__ int s[256];
  int b = blockIdx.x, t = threadIdx.x;
  int base = b * chunk;
  int own = (t < chunk && base + t < N) ? cnt[base + t] : 0;
  s[t] = own;
  __syncthreads();
  for (int d2 = 1; d2 < 256; d2 <<= 1) {
    int v = (t >= d2) ? s[t - d2] : 0;
    __syncthreads();
    s[t] += v;
    __syncthreads();
  }
  int ex = s[t] - own + partialEx[b];
  if (t < chunk && base + t < N) {
    off[base + t] = ex;
    cursor[base + t] = ex;
  }
}

__global__ void pos_kernel(const int* __restrict__ fi,
                           const int* __restrict__ ti, int* __restrict__ cursor,
                           int* __restrict__ pos0, int* __restrict__ pos1,
                           int E) {
  int e = blockIdx.x * 256 + threadIdx.x;
  if (e < E) {
    pos0[e] = atomicAdd(&cursor[ti[e]], 1);
    pos1[e] = atomicAdd(&cursor[fi[e]], 1);
  }
}

// segment sum: one wave per node, contiguous msg rows, f32 accumulate
__global__ __launch_bounds__(256) void agg_csr_kernel(
    const u16* __restrict__ msg, const int* __restrict__ off,
    float* __restrict__ aggf, int N) {
  int n = blockIdx.x * 4 + (threadIdx.x >> 6);
  if (n >= N) return;
  int lane = threadIdx.x & 63;
  int s = off[n], e = off[n + 1];
  float a0 = 0.f, a1 = 0.f;
  const unsigned* m32 = (const unsigned*)msg;
  for (int r = s; r < e; ++r) {
    unsigned d = m32[(size_t)r * 64 + lane];
    a0 += bf2f((u16)(d & 0xffff));
    a1 += bf2f((u16)(d >> 16));
  }
  aggf[(size_t)n * 128 + lane * 2] = a0;
  aggf[(size_t)n * 128 + lane * 2 + 1] = a1;
}

// ---- shared MFMA helpers (verified R1-R3) ----
__device__ inline void stage_w_rw(u16* sW, const u16* __restrict__ src,
                                  int roww, int colofs, int tid) {
  int n = tid >> 1, half = tid & 1;
  const u16* s = src + (size_t)n * roww + colofs + half * 64;
#pragma unroll
  for (int q = 0; q < 8; ++q) {
    uint4 v = *(const uint4*)(s + q * 8);
    int byte = n * 256 + ((half * 128 + q * 16) ^ ((n & 7) << 4));
    *(uint4*)((char*)sW + byte) = v;
  }
}

__device__ inline void mfma_pass(const u16* A, const u16* W, f32x4 acc[8],
                                 int w, int lane) {
  const int cA = lane & 15;
  const int ko = (lane >> 4) * 8;
  const int arow = 16 * w + cA;
#pragma unroll
  for (int kk = 0; kk < 4; ++kk) {
    int ka = (kk * 32 + ko) * 2;
    int sx = ka ^ ((cA & 7) << 4);
    bf16x8 a = *(const bf16x8*)((const char*)A + arow * 256 + sx);
#pragma unroll
    for (int nt = 0; nt < 8; ++nt) {
      bf16x8 bb = *(const bf16x8*)((const char*)W + (nt * 16 + cA) * 256 + sx);
      acc[nt] = __builtin_amdgcn_mfma_f32_16x16x32_bf16(a, bb, acc[nt], 0, 0, 0);
    }
  }
}

__device__ inline void stage_w_512(u16* sW, const u16* __restrict__ src,
                                   int roww, int colofs, int tid) {
  int n = tid >> 2, quarter = tid & 3;
  const u16* s = src + (size_t)n * roww + colofs + quarter * 32;
#pragma unroll
  for (int q = 0; q < 4; ++q) {
    uint4 v = *(const uint4*)(s + q * 8);
    int byte = n * 256 + ((quarter * 64 + q * 16) ^ ((n & 7) << 4));
    *(uint4*)((char*)sW + byte) = v;
  }
}

// Pa = bf16(ns @ W1a), Pb = bf16(ns @ W1b)
__global__ __launch_bounds__(256) void node_partial_kernel(
    const float* __restrict__ ns, const u16* __restrict__ Wt1,
    u16* __restrict__ Pa, u16* __restrict__ Pb, int N) {
  __shared__ u16 sA[64 * 128];
  __shared__ u16 sW[128 * 128];
  const int tid = threadIdx.x;
  const int lane = tid & 63;
  const int w = tid >> 6;
  const int r0 = blockIdx.x * 64;
  {
    int row = tid >> 2, seg = tid & 3;
    int rr = r0 + row;
    if (rr >= N) rr = N - 1;
    const float4* sx = (const float4*)(ns + (size_t)rr * 128 + seg * 32);
#pragma unroll
    for (int q = 0; q < 4; ++q) {
      int byte = row * 256 + ((seg * 64 + q * 16) ^ ((row & 7) << 4));
      *(uint4*)((char*)sA + byte) = pack8(sx[q * 2], sx[q * 2 + 1]);
    }
  }
  stage_w_rw(sW, Wt1, 384, 0, tid);
  __syncthreads();
  f32x4 accA[8] = {};
  mfma_pass(sA, sW, accA, w, lane);
  __syncthreads();
  stage_w_rw(sW, Wt1, 384, 128, tid);
  __syncthreads();
  f32x4 accB[8] = {};
  mfma_pass(sA, sW, accB, w, lane);
#pragma unroll
  for (int nt = 0; nt < 8; ++nt) {
    int col = nt * 16 + (lane & 15);
#pragma unroll
    for (int i = 0; i < 4; ++i) {
      int rr = 16 * w + ((lane >> 4) * 4) + i;
      int row = r0 + rr;
      if (row < N) {
        Pa[(size_t)row * 128 + col] = f2bf(accA[nt][i]);
        Pb[(size_t)row * 128 + col] = f2bf(accB[nt][i]);
      }
    }
  }
}

// Fused edge MLP. MODE 0: dense CSR-slot stores; MODE 1: bf16 atomic scatter.
template <int MODE>
__global__ __launch_bounds__(512, 2) void edge_fused_kernel(
    const float* __restrict__ ef, const int* __restrict__ from_idx,
    const int* __restrict__ to_idx, const u16* __restrict__ Wt1,
    const u16* __restrict__ Wt2, const u16* __restrict__ Wt3,
    const u16* __restrict__ Pa, const u16* __restrict__ Pb,
    const float* __restrict__ b1, const float* __restrict__ b2,
    const float* __restrict__ b3, const int* __restrict__ pos0,
    const int* __restrict__ pos1, u16* __restrict__ out_buf, int E,
    int ntiles) {
  __shared__ u16 sW1c[128 * 128];
  __shared__ u16 sH[128 * 128];
  __shared__ u16 sEF[64 * 128];
  __shared__ int sPos[128];
  const int tid = threadIdx.x;
  const int lane = tid & 63;
  const int wv = tid >> 6;
  const int mw = wv >> 1;
  const int nw = wv & 1;
  const int dir = mw >> 1;
  const int l15 = lane & 15;
  const int lhi = lane >> 4;

  stage_w_512(sW1c, Wt1, 384, 256, tid);

  float b1f[4], b2f[4], b3f[4];
#pragma unroll
  for (int nt = 0; nt < 4; ++nt) {
    int col = (nw << 6) + (nt << 4) + l15;
    b1f[nt] = b1[col];
    b2f[nt] = b2[col];
    b3f[nt] = b3[col];
  }
  bf16x8 w2f[4][4], w3f[4][4];
#pragma unroll
  for (int nt = 0; nt < 4; ++nt) {
    int c = (nw << 6) + (nt << 4) + l15;
#pragma unroll
    for (int kk = 0; kk < 4; ++kk) {
      w2f[nt][kk] = *(const bf16x8*)(Wt2 + (size_t)c * 128 + (kk << 5) + (lhi << 3));
      w3f[nt][kk] = *(const bf16x8*)(Wt3 + (size_t)c * 128 + (kk << 5) + (lhi << 3));
    }
  }
  __syncthreads();

  for (int t = blockIdx.x; t < ntiles; t += gridDim.x) {
    const int e0 = t << 6;
    // P0: prefetch CSR slot positions for this tile's 128 rows
    if (MODE == 0 && tid < 128) {
      int er = tid & 63;
      int e = e0 + er;
      int p = -1;
      if (e < E) p = (tid < 64) ? pos0[e] : pos1[e];
      sPos[tid] = p;
    }
    // Phase A: sEF = ef@W1c + b1
    {
      const int arow = (mw << 4) + l15;
      int e = e0 + arow;
      if (e >= E) e = E - 1;
      const float* ep = ef + (size_t)e * 128 + (lhi << 3);
      bf16x8 efA[4];
#pragma unroll
      for (int kk = 0; kk < 4; ++kk) {
        float4 f0 = *(const float4*)(ep + (kk << 5));
        float4 f1 = *(const float4*)(ep + (kk << 5) + 4);
        uint4 u = pack8(f0, f1);
        efA[kk] = *(bf16x8*)&u;
      }
      f32x4 a1[4] = {};
#pragma unroll
      for (int kk = 0; kk < 4; ++kk) {
#pragma unroll
        for (int nt = 0; nt < 4; ++nt) {
          int c = (nw << 6) + (nt << 4) + l15;
          int sx = ((kk << 6) + (lhi << 4)) ^ ((c & 7) << 4);
          bf16x8 bb = *(const bf16x8*)((const char*)sW1c + c * 256 + sx);
          a1[nt] = __builtin_amdgcn_mfma_f32_16x16x32_bf16(efA[kk], bb, a1[nt], 0, 0, 0);
        }
      }
#pragma unroll
      for (int nt = 0; nt < 4; ++nt) {
        int col = (nw << 6) + (nt << 4) + l15;
#pragma unroll
        for (int i = 0; i < 4; ++i) {
          int row = (mw << 4) + (lhi << 2) + i;
          *(u16*)((char*)sEF + row * 256 + ((col * 2) ^ ((row & 7) << 4))) =
              f2bf(a1[nt][i] + b1f[nt]);
        }
      }
    }
    __syncthreads();
    // Phase C: H1 = relu(sEF + Pa[srcA] + Pb[srcB]) -> sH
#pragma unroll
    for (int it = 0; it < 4; ++it) {
      int row = (tid >> 4) + (it << 5);
      int c8 = tid & 15;
      int er = row & 63, d = row >> 6;
      int ec = e0 + er;
      if (ec >= E) ec = E - 1;
      int fi_e = from_idx[ec], ti_e = to_idx[ec];
      int sA = d ? ti_e : fi_e;
      int sB = d ? fi_e : ti_e;
      uint4 efv = *(const uint4*)((const char*)sEF + er * 256 + ((c8 << 4) ^ ((er & 7) << 4)));
      uint4 pav = *(const uint4*)(Pa + (size_t)sA * 128 + (c8 << 3));
      uint4 pbv = *(const uint4*)(Pb + (size_t)sB * 128 + (c8 << 3));
      const u16* pe = (const u16*)&efv;
      const u16* pa = (const u16*)&pav;
      const u16* pb = (const u16*)&pbv;
      unsigned o[4];
#pragma unroll
      for (int j = 0; j < 4; ++j) {
        float v0 = fmaxf(bf2f(pe[2 * j]) + bf2f(pa[2 * j]) + bf2f(pb[2 * j]), 0.f);
        float v1 = fmaxf(bf2f(pe[2 * j + 1]) + bf2f(pa[2 * j + 1]) + bf2f(pb[2 * j + 1]), 0.f);
        o[j] = (unsigned)f2bf(v0) | ((unsigned)f2bf(v1) << 16);
      }
      *(uint4*)((char*)sH + row * 256 + ((c8 << 4) ^ ((row & 7) << 4))) = *(uint4*)o;
    }
    __syncthreads();
    // Phase D: acc2 = H1 @ W2
    bf16x8 hA[2][4];
#pragma unroll
    for (int m = 0; m < 2; ++m) {
      int ra = (mw << 5) + (m << 4) + l15;
#pragma unroll
      for (int kk = 0; kk < 4; ++kk) {
        int sx = ((kk << 6) + (lhi << 4)) ^ ((ra & 7) << 4);
        hA[m][kk] = *(const bf16x8*)((const char*)sH + ra * 256 + sx);
      }
    }
    f32x4 acc2[2][4] = {};
#pragma unroll
    for (int kk = 0; kk < 4; ++kk)
#pragma unroll
      for (int nt = 0; nt < 4; ++nt)
#pragma unroll
        for (int m = 0; m < 2; ++m)
          acc2[m][nt] = __builtin_amdgcn_mfma_f32_16x16x32_bf16(
              hA[m][kk], w2f[nt][kk], acc2[m][nt], 0, 0, 0);
    __syncthreads();
    // Phase E: H2 = relu(acc2 + b2) -> sH
#pragma unroll
    for (int m = 0; m < 2; ++m) {
#pragma unroll
      for (int i = 0; i < 4; ++i) {
        int rl = (mw << 5) + (m << 4) + (lhi << 2) + i;
#pragma unroll
        for (int nt = 0; nt < 4; ++nt) {
          int col = (nw << 6) + (nt << 4) + l15;
          float v = fmaxf(acc2[m][nt][i] + b2f[nt], 0.f);
          *(u16*)((char*)sH + rl * 256 + ((col * 2) ^ ((rl & 7) << 4))) = f2bf(v);
        }
      }
    }
    __syncthreads();
    // Phase F: acc3 = H2 @ W3
#pragma unroll
    for (int m = 0; m < 2; ++m) {
      int ra = (mw << 5) + (m << 4) + l15;
#pragma unroll
      for (int kk = 0; kk < 4; ++kk) {
        int sx = ((kk << 6) + (lhi << 4)) ^ ((ra & 7) << 4);
        hA[m][kk] = *(const bf16x8*)((const char*)sH + ra * 256 + sx);
      }
    }
    f32x4 acc3[2][4] = {};
#pragma unroll
    for (int kk = 0; kk < 4; ++kk)
#pragma unroll
      for (int nt = 0; nt < 4; ++nt)
#pragma unroll
        for (int m = 0; m < 2; ++m)
          acc3[m][nt] = __builtin_amdgcn_mfma_f32_16x16x32_bf16(
              hA[m][kk], w3f[nt][kk], acc3[m][nt], 0, 0, 0);

    if (MODE == 0) {
      __syncthreads();  // F reads of sH done
      // OUT = acc3 + b3 -> sH (bf16, swizzled)
#pragma unroll
      for (int m = 0; m < 2; ++m) {
#pragma unroll
        for (int i = 0; i < 4; ++i) {
          int rl = (mw << 5) + (m << 4) + (lhi << 2) + i;
#pragma unroll
          for (int nt = 0; nt < 4; ++nt) {
            int col = (nw << 6) + (nt << 4) + l15;
            *(u16*)((char*)sH + rl * 256 + ((col * 2) ^ ((rl & 7) << 4))) =
                f2bf(acc3[m][nt][i] + b3f[nt]);
          }
        }
      }
      __syncthreads();
      // coalesced store to msg[pos]
#pragma unroll
      for (int it = 0; it < 4; ++it) {
        int task = tid + (it << 9);
        int row = task >> 4, c8 = task & 15;
        int p = sPos[row];
        if (p >= 0) {
          uint4 v = *(const uint4*)((const char*)sH + row * 256 +
                                    ((c8 << 4) ^ ((row & 7) << 4)));
          *(uint4*)(out_buf + (size_t)p * 128 + (c8 << 3)) = v;
        }
      }
      __syncthreads();  // protect sPos/sH before next tile
    } else {
      // atomic bf16 scatter (fallback)
#pragma unroll
      for (int m = 0; m < 2; ++m) {
#pragma unroll
        for (int i = 0; i < 4; ++i) {
          int er = ((mw & 1) << 5) + (m << 4) + (lhi << 2) + i;
          int e = e0 + er;
#pragma unroll
          for (int nt = 0; nt < 4; ++nt) {
            int col = (nw << 6) + (nt << 4) + l15;
            float v = acc3[m][nt][i] + b3f[nt];
            float vp = __shfl_xor(v, 1);
            if (e < E && !(lane & 1)) {
              int dest = dir ? from_idx[e] : to_idx[e];
              unsigned d2 = (unsigned)f2bf(v) | ((unsigned)f2bf(vp) << 16);
              atomic_pk_add_bf16(out_buf + (size_t)dest * 128 + col, d2);
            }
          }
        }
      }
    }
  }
}

__global__ __launch_bounds__(256) void gru_kernel(
    const float* __restrict__ x, const float* __restrict__ h,
    const u16* __restrict__ Wt, const u16* __restrict__ Ut,
    const float* __restrict__ b, const float* __restrict__ c,
    float* __restrict__ out, int nrows) {
  __shared__ u16 sX[64 * 128];
  __shared__ u16 sH[64 * 128];
  __shared__ u16 sW[128 * 128];
  const int tid = threadIdx.x;
  const int lane = tid & 63;
  const int w = tid >> 6;
  const int r0 = blockIdx.x * 64;
  {
    int row = tid >> 2, seg = tid & 3;
    int rr = r0 + row;
    if (rr >= nrows) rr = nrows - 1;
    const float4* sx = (const float4*)(x + (size_t)rr * 128 + seg * 32);
    const float4* sh = (const float4*)(h + (size_t)rr * 128 + seg * 32);
#pragma unroll
    for (int q = 0; q < 4; ++q) {
      int byte = row * 256 + ((seg * 64 + q * 16) ^ ((row & 7) << 4));
      *(uint4*)((char*)sX + byte) = pack8(sx[q * 2], sx[q * 2 + 1]);
      *(uint4*)((char*)sH + byte) = pack8(sh[q * 2], sh[q * 2 + 1]);
    }
  }
  f32x4 ar[8] = {}, az[8] = {}, ai[8] = {}, ah[8] = {};
  stage_w_rw(sW, Wt + 0 * 16384, 128, 0, tid); __syncthreads();
  mfma_pass(sX, sW, ar, w, lane); __syncthreads();
  stage_w_rw(sW, Ut + 0 * 16384, 128, 0, tid); __syncthreads();
  mfma_pass(sH, sW, ar, w, lane); __syncthreads();
  stage_w_rw(sW, Wt + 1 * 16384, 128, 0, tid); __syncthreads();
  mfma_pass(sX, sW, az, w, lane); __syncthreads();
  stage_w_rw(sW, Ut + 1 * 16384, 128, 0, tid); __syncthreads();
  mfma_pass(sH, sW, az, w, lane); __syncthreads();
  stage_w_rw(sW, Wt + 2 * 16384, 128, 0, tid); __syncthreads();
  mfma_pass(sX, sW, ai, w, lane); __syncthreads();
  stage_w_rw(sW, Ut + 2 * 16384, 128, 0, tid); __syncthreads();
  mfma_pass(sH, sW, ah, w, lane);
#pragma unroll
  for (int nt = 0; nt < 8; ++nt) {
    int col = nt * 16 + (lane & 15);
    float brc = b[col] + c[col];
    float bzc = b[128 + col] + c[128 + col];
    float bi = b[256 + col];
    float bc2 = c[256 + col];
#pragma unroll
    for (int i = 0; i < 4; ++i) {
      int rloc = 16 * w + ((lane >> 4) * 4) + i;
      int row = r0 + rloc;
      if (row < nrows) {
        float rg = 1.f / (1.f + __expf(-(ar[nt][i] + brc)));
        float zg = 1.f / (1.f + __expf(-(az[nt][i] + bzc)));
        float pre = ai[nt][i] + bi + rg * (ah[nt][i] + bc2);
        float ng = 2.f / (1.f + __expf(-2.f * pre)) - 1.f;
        float hf = h[(size_t)row * 128 + col];
        out[(size_t)row * 128 + col] = (1.f - zg) * ng + zg * hf;
      }
    }
  }
}

extern "C" void kernel_launch(void* const* d_in, const int* in_sizes, int n_in,
                              void* d_out, int out_size, void* d_ws,
                              size_t ws_size, hipStream_t stream) {
  const float* ns = (const float*)d_in[0];
  const float* ef = (const float*)d_in[1];
  const int* from_idx = (const int*)d_in[2];
  const int* to_idx = (const int*)d_in[3];
  const float* mW1 = (const float*)d_in[5];
  const float* mb1 = (const float*)d_in[6];
  const float* mW2 = (const float*)d_in[7];
  const float* mb2 = (const float*)d_in[8];
  const float* mW3 = (const float*)d_in[9];
  const float* mb3 = (const float*)d_in[10];
  const float* gW[3] = {(const float*)d_in[11], (const float*)d_in[15], (const float*)d_in[19]};
  const float* gU[3] = {(const float*)d_in[12], (const float*)d_in[16], (const float*)d_in[20]};
  const float* gb[3] = {(const float*)d_in[13], (const float*)d_in[17], (const float*)d_in[21]};
  const float* gc[3] = {(const float*)d_in[14], (const float*)d_in[18], (const float*)d_in[22]};

  const int N = in_sizes[0] / 128;
  const int E = in_sizes[1] / 128;

  // workspace layout
  char* base = (char*)d_ws;
  size_t cur = 0;
  auto alloc = [&](size_t bytes) {
    size_t p = cur;
    cur = (cur + bytes + 255) & ~(size_t)255;
    return (void*)(base + p);
  };
  float* aggf = (float*)alloc((size_t)N * 128 * 4);
  u16* Pa = (u16*)alloc((size_t)N * 128 * 2);
  u16* Pb = (u16*)alloc((size_t)N * 128 * 2);
  u16* Wt1 = (u16*)alloc(384 * 128 * 2);
  u16* Wt2 = (u16*)alloc(128 * 128 * 2);
  u16* Wt3 = (u16*)alloc(128 * 128 * 2);
  u16 *gWt[3], *gUt[3];
  for (int i = 0; i < 3; ++i) {
    gWt[i] = (u16*)alloc(384 * 128 * 2);
    gUt[i] = (u16*)alloc(384 * 128 * 2);
  }
  int* cnt = (int*)alloc((size_t)N * 4);
  int* off = (int*)alloc((size_t)(N + 1) * 4);
  int* cursor = (int*)alloc((size_t)N * 4);
  int* partial = (int*)alloc(256 * 4);
  int* pos0 = (int*)alloc((size_t)E * 4);
  int* pos1 = (int*)alloc((size_t)E * 4);
  u16* aggb = (u16*)alloc((size_t)N * 128 * 2);  // fallback accumulate buffer
  size_t fixed_end = cur;
  u16* msg = (u16*)alloc((size_t)2 * E * 128 * 2);
  bool csr_ok = (cur <= ws_size);

  auto T = [&](const float* s, u16* d, int R, int C) {
    transpose_bf16_kernel<<<(R * C + 255) / 256, 256, 0, stream>>>(s, d, R, C);
  };
  T(mW1, Wt1, 384, 128);
  T(mW2, Wt2, 128, 128);
  T(mW3, Wt3, 128, 128);
  for (int i = 0; i < 3; ++i) { T(gW[i], gWt[i], 128, 384); T(gU[i], gUt[i], 128, 384); }

  node_partial_kernel<<<(N + 63) / 64, 256, 0, stream>>>(ns, Wt1, Pa, Pb, N);

  int ntiles = (E + 63) / 64;

  if (csr_ok) {
    // build CSR slot assignment
    hipMemsetAsync(cnt, 0, (size_t)N * 4, stream);
    count_kernel<<<(E + 255) / 256, 256, 0, stream>>>(from_idx, to_idx, cnt, E);
    int chunk = (N + 255) / 256;
    scan1_kernel<<<256, 256, 0, stream>>>(cnt, partial, N, chunk);
    scan2_kernel<<<1, 256, 0, stream>>>(partial, off, N);
    scan3_kernel<<<256, 256, 0, stream>>>(cnt, partial, off, cursor, N, chunk);
    pos_kernel<<<(E + 255) / 256, 256, 0, stream>>>(from_idx, to_idx, cursor,
                                                    pos0, pos1, E);
    int egrid = ntiles < 1024 ? ntiles : 1024;
    edge_fused_kernel<0><<<egrid, 512, 0, stream>>>(
        ef, from_idx, to_idx, Wt1, Wt2, Wt3, Pa, Pb, mb1, mb2, mb3, pos0, pos1,
        msg, E, ntiles);
    agg_csr_kernel<<<(N + 3) / 4, 256, 0, stream>>>(msg, off, aggf, N);
  } else {
    hipMemsetAsync(aggb, 0, (size_t)N * 128 * 2, stream);
    int egrid = ntiles < 512 ? ntiles : 512;
    edge_fused_kernel<1><<<egrid, 512, 0, stream>>>(
        ef, from_idx, to_idx, Wt1, Wt2, Wt3, Pa, Pb, mb1, mb2, mb3, pos0, pos1,
        aggb, E, ntiles);
    bf16_to_f32_kernel<<<(N * 16 + 255) / 256, 256, 0, stream>>>(aggb, aggf, N * 16);
  }
  (void)fixed_end;

  float* h1 = (float*)d_out;
  float* h2 = aggf;
  int gblocks = (N + 63) / 64;
  gru_kernel<<<gblocks, 256, 0, stream>>>(ns, aggf, gWt[0], gUt[0], gb[0], gc[0], h1, N);
  gru_kernel<<<gblocks, 256, 0, stream>>>(aggf, h1, gWt[1], gUt[1], gb[1], gc[1], h2, N);
  gru_kernel<<<gblocks, 256, 0, stream>>>(h1, h2, gWt[2], gUt[2], gb[2], gc[2], (float*)d_out, N);
}

// Round 5
// 625.412 us; speedup vs baseline: 1.9230x; 1.2089x over previous
//
#include <hip/hip_runtime.h>

typedef unsigned short u16;
typedef __attribute__((ext_vector_type(8))) short bf16x8;
typedef __attribute__((ext_vector_type(4))) float f32x4;

__device__ inline u16 f2bf(float f) {
  unsigned int u = __float_as_uint(f);
  u += 0x7fffu + ((u >> 16) & 1u);
  return (u16)(u >> 16);
}
__device__ inline float bf2f(u16 v) {
  return __uint_as_float((unsigned)v << 16);
}

__device__ inline uint4 pack8(float4 a, float4 b) {
  uint4 r;
  r.x = (unsigned)f2bf(a.x) | ((unsigned)f2bf(a.y) << 16);
  r.y = (unsigned)f2bf(a.z) | ((unsigned)f2bf(a.w) << 16);
  r.z = (unsigned)f2bf(b.x) | ((unsigned)f2bf(b.y) << 16);
  r.w = (unsigned)f2bf(b.z) | ((unsigned)f2bf(b.w) << 16);
  return r;
}

__device__ inline void atomic_pk_add_bf16(u16* p, unsigned v) {
  asm volatile("global_atomic_pk_add_bf16 %0, %1, off" : : "v"(p), "v"(v)
               : "memory");
}

// ---- fused one-shot weight transpose: dst[c*R+r] = bf16(src[r*C+c]) ----
struct TransDesc {
  const float* src[9];
  u16* dst[9];
  int R[9];
  int C[9];
  int pre[10];
};

__global__ void transpose_all_kernel(TransDesc td) {
  int t = blockIdx.x * 256 + threadIdx.x;
  if (t >= td.pre[9]) return;
  int seg = 0;
  while (t >= td.pre[seg + 1]) ++seg;
  int local = t - td.pre[seg];
  int C = td.C[seg], R = td.R[seg];
  int r = local / C, c = local - r * C;
  td.dst[seg][(size_t)c * R + r] = f2bf(td.src[seg][local]);
}

__global__ void bf16_to_f32_kernel(const u16* __restrict__ in,
                                   float* __restrict__ out, int n8) {
  int t = blockIdx.x * 256 + threadIdx.x;
  if (t < n8) {
    uint4 v = ((const uint4*)in)[t];
    u16* p = (u16*)&v;
    float4 o0 = {bf2f(p[0]), bf2f(p[1]), bf2f(p[2]), bf2f(p[3])};
    float4 o1 = {bf2f(p[4]), bf2f(p[5]), bf2f(p[6]), bf2f(p[7])};
    ((float4*)out)[t * 2] = o0;
    ((float4*)out)[t * 2 + 1] = o1;
  }
}

// ---------------- CSR build ----------------
__global__ void count_kernel(const int* __restrict__ fi,
                             const int* __restrict__ ti,
                             int* __restrict__ cnt, int E) {
  int e = blockIdx.x * 256 + threadIdx.x;
  if (e < E) {
    atomicAdd(&cnt[ti[e]], 1);
    atomicAdd(&cnt[fi[e]], 1);
  }
}

__global__ void scan1_kernel(const int* __restrict__ cnt,
                             int* __restrict__ partial, int N, int chunk) {
  __shared__ int sdata[256];
  int b = blockIdx.x, t = threadIdx.x;
  int base = b * chunk;
  int sum = 0;
  for (int i = t; i < chunk; i += 256) {
    int idx = base + i;
    if (idx < N) sum += cnt[idx];
  }
  sdata[t] = sum;
  __syncthreads();
  for (int s2 = 128; s2 > 0; s2 >>= 1) {
    if (t < s2) sdata[t] += sdata[t + s2];
    __syncthreads();
  }
  if (t == 0) partial[b] = sdata[0];
}

__global__ void scan2_kernel(int* __restrict__ partial, int* __restrict__ off,
                             int N) {
  __shared__ int s[256];
  int t = threadIdx.x;
  int own = partial[t];
  s[t] = own;
  __syncthreads();
  for (int d2 = 1; d2 < 256; d2 <<= 1) {
    int v = (t >= d2) ? s[t - d2] : 0;
    __syncthreads();
    s[t] += v;
    __syncthreads();
  }
  partial[t] = s[t] - own;           // exclusive
  if (t == 255) off[N] = s[255];     // total = 2E
}

__global__ void scan3_kernel(const int* __restrict__ cnt,
                             const int* __restrict__ partialEx,
                             int* __restrict__ off, int* __restrict__ cursor,
                             int N, int chunk) {
  __shared__ int s[256];
  int b = blockIdx.x, t = threadIdx.x;
  int base = b * chunk;
  int own = (t < chunk && base + t < N) ? cnt[base + t] : 0;
  s[t] = own;
  __syncthreads();
  for (int d2 = 1; d2 < 256; d2 <<= 1) {
    int v = (t >= d2) ? s[t - d2] : 0;
    __syncthreads();
    s[t] += v;
    __syncthreads();
  }
  int ex = s[t] - own + partialEx[b];
  if (t < chunk && base + t < N) {
    off[base + t] = ex;
    cursor[base + t] = ex;
  }
}

__global__ void pos_kernel(const int* __restrict__ fi,
                           const int* __restrict__ ti, int* __restrict__ cursor,
                           int* __restrict__ pos0, int* __restrict__ pos1,
                           int E) {
  int e = blockIdx.x * 256 + threadIdx.x;
  if (e < E) {
    pos0[e] = atomicAdd(&cursor[ti[e]], 1);
    pos1[e] = atomicAdd(&cursor[fi[e]], 1);
  }
}

// segment sum: one wave per node, contiguous msg rows, f32 accumulate
__global__ __launch_bounds__(256) void agg_csr_kernel(
    const u16* __restrict__ msg, const int* __restrict__ off,
    float* __restrict__ aggf, int N) {
  int n = blockIdx.x * 4 + (threadIdx.x >> 6);
  if (n >= N) return;
  int lane = threadIdx.x & 63;
  int s = off[n], e = off[n + 1];
  float a0 = 0.f, a1 = 0.f, b0 = 0.f, b1 = 0.f;
  const unsigned* m32 = (const unsigned*)msg;
  int r = s;
  for (; r + 1 < e; r += 2) {
    unsigned d0 = m32[(size_t)r * 64 + lane];
    unsigned d1 = m32[(size_t)(r + 1) * 64 + lane];
    a0 += bf2f((u16)(d0 & 0xffff));
    a1 += bf2f((u16)(d0 >> 16));
    b0 += bf2f((u16)(d1 & 0xffff));
    b1 += bf2f((u16)(d1 >> 16));
  }
  if (r < e) {
    unsigned d0 = m32[(size_t)r * 64 + lane];
    a0 += bf2f((u16)(d0 & 0xffff));
    a1 += bf2f((u16)(d0 >> 16));
  }
  aggf[(size_t)n * 128 + lane * 2] = a0 + b0;
  aggf[(size_t)n * 128 + lane * 2 + 1] = a1 + b1;
}

// ---- shared MFMA helpers (verified R1-R4) ----
__device__ inline void stage_w_rw(u16* sW, const u16* __restrict__ src,
                                  int roww, int colofs, int tid) {
  int n = tid >> 1, half = tid & 1;
  const u16* s = src + (size_t)n * roww + colofs + half * 64;
#pragma unroll
  for (int q = 0; q < 8; ++q) {
    uint4 v = *(const uint4*)(s + q * 8);
    int byte = n * 256 + ((half * 128 + q * 16) ^ ((n & 7) << 4));
    *(uint4*)((char*)sW + byte) = v;
  }
}

__device__ inline void mfma_pass(const u16* A, const u16* W, f32x4 acc[8],
                                 int w, int lane) {
  const int cA = lane & 15;
  const int ko = (lane >> 4) * 8;
  const int arow = 16 * w + cA;
#pragma unroll
  for (int kk = 0; kk < 4; ++kk) {
    int ka = (kk * 32 + ko) * 2;
    int sx = ka ^ ((cA & 7) << 4);
    bf16x8 a = *(const bf16x8*)((const char*)A + arow * 256 + sx);
#pragma unroll
    for (int nt = 0; nt < 8; ++nt) {
      bf16x8 bb = *(const bf16x8*)((const char*)W + (nt * 16 + cA) * 256 + sx);
      acc[nt] = __builtin_amdgcn_mfma_f32_16x16x32_bf16(a, bb, acc[nt], 0, 0, 0);
    }
  }
}

// relu-free bf16 writeback of acc fragments into swizzled LDS
__device__ inline void write_h_lds(u16* sH, const f32x4 acc[8], int w,
                                   int lane) {
#pragma unroll
  for (int nt = 0; nt < 8; ++nt) {
    int col = nt * 16 + (lane & 15);
#pragma unroll
    for (int i = 0; i < 4; ++i) {
      int rr = 16 * w + ((lane >> 4) * 4) + i;
      *(u16*)((char*)sH + rr * 256 + ((col * 2) ^ ((rr & 7) << 4))) =
          f2bf(acc[nt][i]);
    }
  }
}

__device__ inline void stage_w_512(u16* sW, const u16* __restrict__ src,
                                   int roww, int colofs, int tid) {
  int n = tid >> 2, quarter = tid & 3;
  const u16* s = src + (size_t)n * roww + colofs + quarter * 32;
#pragma unroll
  for (int q = 0; q < 4; ++q) {
    uint4 v = *(const uint4*)(s + q * 8);
    int byte = n * 256 + ((quarter * 64 + q * 16) ^ ((n & 7) << 4));
    *(uint4*)((char*)sW + byte) = v;
  }
}

// Pa = bf16(ns @ W1a), Pb = bf16(ns @ W1b)
__global__ __launch_bounds__(256) void node_partial_kernel(
    const float* __restrict__ ns, const u16* __restrict__ Wt1,
    u16* __restrict__ Pa, u16* __restrict__ Pb, int N) {
  __shared__ u16 sA[64 * 128];
  __shared__ u16 sW[128 * 128];
  const int tid = threadIdx.x;
  const int lane = tid & 63;
  const int w = tid >> 6;
  const int r0 = blockIdx.x * 64;
  {
    int row = tid >> 2, seg = tid & 3;
    int rr = r0 + row;
    if (rr >= N) rr = N - 1;
    const float4* sx = (const float4*)(ns + (size_t)rr * 128 + seg * 32);
#pragma unroll
    for (int q = 0; q < 4; ++q) {
      int byte = row * 256 + ((seg * 64 + q * 16) ^ ((row & 7) << 4));
      *(uint4*)((char*)sA + byte) = pack8(sx[q * 2], sx[q * 2 + 1]);
    }
  }
  stage_w_rw(sW, Wt1, 384, 0, tid);
  __syncthreads();
  f32x4 accA[8] = {};
  mfma_pass(sA, sW, accA, w, lane);
  __syncthreads();
  stage_w_rw(sW, Wt1, 384, 128, tid);
  __syncthreads();
  f32x4 accB[8] = {};
  mfma_pass(sA, sW, accB, w, lane);
#pragma unroll
  for (int nt = 0; nt < 8; ++nt) {
    int col = nt * 16 + (lane & 15);
#pragma unroll
    for (int i = 0; i < 4; ++i) {
      int rr = 16 * w + ((lane >> 4) * 4) + i;
      int row = r0 + rr;
      if (row < N) {
        Pa[(size_t)row * 128 + col] = f2bf(accA[nt][i]);
        Pb[(size_t)row * 128 + col] = f2bf(accB[nt][i]);
      }
    }
  }
}

// Fused edge MLP. MODE 0: dense CSR-slot stores; MODE 1: bf16 atomic scatter.
// LDS: sW1c 32K + sH 32K + sPos 512B = 66048 B -> 2 blocks/CU.
template <int MODE>
__global__ __launch_bounds__(512, 2) void edge_fused_kernel(
    const float* __restrict__ ef, const int* __restrict__ from_idx,
    const int* __restrict__ to_idx, const u16* __restrict__ Wt1,
    const u16* __restrict__ Wt2, const u16* __restrict__ Wt3,
    const u16* __restrict__ Pa, const u16* __restrict__ Pb,
    const float* __restrict__ b1, const float* __restrict__ b2,
    const float* __restrict__ b3, const int* __restrict__ pos0,
    const int* __restrict__ pos1, u16* __restrict__ out_buf, int E,
    int ntiles) {
  __shared__ u16 sW1c[128 * 128];
  __shared__ u16 sH[128 * 128];
  __shared__ int sPos[128];
  const int tid = threadIdx.x;
  const int lane = tid & 63;
  const int wv = tid >> 6;
  const int mw = wv >> 1;
  const int nw = wv & 1;
  const int dir = mw >> 1;
  const int l15 = lane & 15;
  const int lhi = lane >> 4;

  stage_w_512(sW1c, Wt1, 384, 256, tid);

  float b1f[4], b2f[4], b3f[4];
#pragma unroll
  for (int nt = 0; nt < 4; ++nt) {
    int col = (nw << 6) + (nt << 4) + l15;
    b1f[nt] = b1[col];
    b2f[nt] = b2[col];
    b3f[nt] = b3[col];
  }
  bf16x8 w2f[4][4], w3f[4][4];
#pragma unroll
  for (int nt = 0; nt < 4; ++nt) {
    int c = (nw << 6) + (nt << 4) + l15;
#pragma unroll
    for (int kk = 0; kk < 4; ++kk) {
      w2f[nt][kk] = *(const bf16x8*)(Wt2 + (size_t)c * 128 + (kk << 5) + (lhi << 3));
      w3f[nt][kk] = *(const bf16x8*)(Wt3 + (size_t)c * 128 + (kk << 5) + (lhi << 3));
    }
  }
  __syncthreads();

  for (int t = blockIdx.x; t < ntiles; t += gridDim.x) {
    const int e0 = t << 6;
    // P0: prefetch CSR slot positions for this tile's 128 rows
    if (MODE == 0 && tid < 128) {
      int er = tid & 63;
      int e = e0 + er;
      int p = -1;
      if (e < E) p = (tid < 64) ? pos0[e] : pos1[e];
      sPos[tid] = p;
    }
    // Phase A: EF = ef@W1c + b1 -> BOTH halves of sH (shared by dirs)
    {
      const int arow = (mw << 4) + l15;
      int e = e0 + arow;
      if (e >= E) e = E - 1;
      const float* ep = ef + (size_t)e * 128 + (lhi << 3);
      bf16x8 efA[4];
#pragma unroll
      for (int kk = 0; kk < 4; ++kk) {
        float4 f0 = *(const float4*)(ep + (kk << 5));
        float4 f1 = *(const float4*)(ep + (kk << 5) + 4);
        uint4 u = pack8(f0, f1);
        efA[kk] = *(bf16x8*)&u;
      }
      f32x4 a1[4] = {};
#pragma unroll
      for (int kk = 0; kk < 4; ++kk) {
#pragma unroll
        for (int nt = 0; nt < 4; ++nt) {
          int c = (nw << 6) + (nt << 4) + l15;
          int sx = ((kk << 6) + (lhi << 4)) ^ ((c & 7) << 4);
          bf16x8 bb = *(const bf16x8*)((const char*)sW1c + c * 256 + sx);
          a1[nt] = __builtin_amdgcn_mfma_f32_16x16x32_bf16(efA[kk], bb, a1[nt], 0, 0, 0);
        }
      }
#pragma unroll
      for (int nt = 0; nt < 4; ++nt) {
        int col = (nw << 6) + (nt << 4) + l15;
#pragma unroll
        for (int i = 0; i < 4; ++i) {
          int row = (mw << 4) + (lhi << 2) + i;
          u16 val = f2bf(a1[nt][i] + b1f[nt]);
          int sw = (col * 2) ^ ((row & 7) << 4);
          *(u16*)((char*)sH + row * 256 + sw) = val;
          *(u16*)((char*)sH + (row + 64) * 256 + sw) = val;
        }
      }
    }
    __syncthreads();
    // Phase C: sH[row] = relu(sH[row] + Pa[srcA] + Pb[srcB])  (in-place RMW)
#pragma unroll
    for (int it = 0; it < 4; ++it) {
      int row = (tid >> 4) + (it << 5);
      int c8 = tid & 15;
      int er = row & 63, d = row >> 6;
      int ec = e0 + er;
      if (ec >= E) ec = E - 1;
      int fi_e = from_idx[ec], ti_e = to_idx[ec];
      int sA = d ? ti_e : fi_e;
      int sB = d ? fi_e : ti_e;
      char* hptr = (char*)sH + row * 256 + ((c8 << 4) ^ ((row & 7) << 4));
      uint4 efv = *(const uint4*)hptr;
      uint4 pav = *(const uint4*)(Pa + (size_t)sA * 128 + (c8 << 3));
      uint4 pbv = *(const uint4*)(Pb + (size_t)sB * 128 + (c8 << 3));
      const u16* pe = (const u16*)&efv;
      const u16* pa = (const u16*)&pav;
      const u16* pb = (const u16*)&pbv;
      unsigned o[4];
#pragma unroll
      for (int j = 0; j < 4; ++j) {
        float v0 = fmaxf(bf2f(pe[2 * j]) + bf2f(pa[2 * j]) + bf2f(pb[2 * j]), 0.f);
        float v1 = fmaxf(bf2f(pe[2 * j + 1]) + bf2f(pa[2 * j + 1]) + bf2f(pb[2 * j + 1]), 0.f);
        o[j] = (unsigned)f2bf(v0) | ((unsigned)f2bf(v1) << 16);
      }
      *(uint4*)hptr = *(uint4*)o;
    }
    __syncthreads();
    // Phase D: acc2 = H1 @ W2
    bf16x8 hA[2][4];
#pragma unroll
    for (int m = 0; m < 2; ++m) {
      int ra = (mw << 5) + (m << 4) + l15;
#pragma unroll
      for (int kk = 0; kk < 4; ++kk) {
        int sx = ((kk << 6) + (lhi << 4)) ^ ((ra & 7) << 4);
        hA[m][kk] = *(const bf16x8*)((const char*)sH + ra * 256 + sx);
      }
    }
    f32x4 acc2[2][4] = {};
#pragma unroll
    for (int kk = 0; kk < 4; ++kk)
#pragma unroll
      for (int nt = 0; nt < 4; ++nt)
#pragma unroll
        for (int m = 0; m < 2; ++m)
          acc2[m][nt] = __builtin_amdgcn_mfma_f32_16x16x32_bf16(
              hA[m][kk], w2f[nt][kk], acc2[m][nt], 0, 0, 0);
    __syncthreads();
    // Phase E: H2 = relu(acc2 + b2) -> sH
#pragma unroll
    for (int m = 0; m < 2; ++m) {
#pragma unroll
      for (int i = 0; i < 4; ++i) {
        int rl = (mw << 5) + (m << 4) + (lhi << 2) + i;
#pragma unroll
        for (int nt = 0; nt < 4; ++nt) {
          int col = (nw << 6) + (nt << 4) + l15;
          float v = fmaxf(acc2[m][nt][i] + b2f[nt], 0.f);
          *(u16*)((char*)sH + rl * 256 + ((col * 2) ^ ((rl & 7) << 4))) = f2bf(v);
        }
      }
    }
    __syncthreads();
    // Phase F: acc3 = H2 @ W3
#pragma unroll
    for (int m = 0; m < 2; ++m) {
      int ra = (mw << 5) + (m << 4) + l15;
#pragma unroll
      for (int kk = 0; kk < 4; ++kk) {
        int sx = ((kk << 6) + (lhi << 4)) ^ ((ra & 7) << 4);
        hA[m][kk] = *(const bf16x8*)((const char*)sH + ra * 256 + sx);
      }
    }
    f32x4 acc3[2][4] = {};
#pragma unroll
    for (int kk = 0; kk < 4; ++kk)
#pragma unroll
      for (int nt = 0; nt < 4; ++nt)
#pragma unroll
        for (int m = 0; m < 2; ++m)
          acc3[m][nt] = __builtin_amdgcn_mfma_f32_16x16x32_bf16(
              hA[m][kk], w3f[nt][kk], acc3[m][nt], 0, 0, 0);

    if (MODE == 0) {
      __syncthreads();  // F reads of sH done
      // OUT = acc3 + b3 -> sH (bf16, swizzled)
#pragma unroll
      for (int m = 0; m < 2; ++m) {
#pragma unroll
        for (int i = 0; i < 4; ++i) {
          int rl = (mw << 5) + (m << 4) + (lhi << 2) + i;
#pragma unroll
          for (int nt = 0; nt < 4; ++nt) {
            int col = (nw << 6) + (nt << 4) + l15;
            *(u16*)((char*)sH + rl * 256 + ((col * 2) ^ ((rl & 7) << 4))) =
                f2bf(acc3[m][nt][i] + b3f[nt]);
          }
        }
      }
      __syncthreads();
      // coalesced store to msg[pos]
#pragma unroll
      for (int it = 0; it < 4; ++it) {
        int task = tid + (it << 9);
        int row = task >> 4, c8 = task & 15;
        int p = sPos[row];
        if (p >= 0) {
          uint4 v = *(const uint4*)((const char*)sH + row * 256 +
                                    ((c8 << 4) ^ ((row & 7) << 4)));
          *(uint4*)(out_buf + (size_t)p * 128 + (c8 << 3)) = v;
        }
      }
      __syncthreads();  // protect sPos/sH before next tile
    } else {
      // atomic bf16 scatter (fallback)
#pragma unroll
      for (int m = 0; m < 2; ++m) {
#pragma unroll
        for (int i = 0; i < 4; ++i) {
          int er = ((mw & 1) << 5) + (m << 4) + (lhi << 2) + i;
          int e = e0 + er;
#pragma unroll
          for (int nt = 0; nt < 4; ++nt) {
            int col = (nw << 6) + (nt << 4) + l15;
            float v = acc3[m][nt][i] + b3f[nt];
            float vp = __shfl_xor(v, 1);
            if (e < E && !(lane & 1)) {
              int dest = dir ? from_idx[e] : to_idx[e];
              unsigned d2 = (unsigned)f2bf(v) | ((unsigned)f2bf(vp) << 16);
              atomic_pk_add_bf16(out_buf + (size_t)dest * 128 + col, d2);
            }
          }
        }
      }
      __syncthreads();
    }
  }
}

// Fused 3-GRU chain: h1=gru0(ns,agg); h2=gru1(agg,h1); h3=gru2(h1,h2)->out.
// h1/h2 ping-pong through sX/sG; f32 passthrough stays in registers.
__global__ __launch_bounds__(256, 2) void gru3_kernel(
    const float* __restrict__ ns, const float* __restrict__ aggf,
    const u16* __restrict__ g0W, const u16* __restrict__ g0U,
    const u16* __restrict__ g1W, const u16* __restrict__ g1U,
    const u16* __restrict__ g2W, const u16* __restrict__ g2U,
    const float* __restrict__ b0, const float* __restrict__ c0,
    const float* __restrict__ b1, const float* __restrict__ c1,
    const float* __restrict__ b2, const float* __restrict__ c2,
    float* __restrict__ out, int N) {
  __shared__ u16 sX[64 * 128];  // ns -> later h1
  __shared__ u16 sG[64 * 128];  // agg -> later h2
  __shared__ u16 sW[128 * 128];
  const int tid = threadIdx.x;
  const int lane = tid & 63;
  const int w = tid >> 6;
  const int r0 = blockIdx.x * 64;
  {
    int row = tid >> 2, seg = tid & 3;
    int rr = r0 + row;
    if (rr >= N) rr = N - 1;
    const float4* sx = (const float4*)(ns + (size_t)rr * 128 + seg * 32);
    const float4* sh = (const float4*)(aggf + (size_t)rr * 128 + seg * 32);
#pragma unroll
    for (int q = 0; q < 4; ++q) {
      int byte = row * 256 + ((seg * 64 + q * 16) ^ ((row & 7) << 4));
      *(uint4*)((char*)sX + byte) = pack8(sx[q * 2], sx[q * 2 + 1]);
      *(uint4*)((char*)sG + byte) = pack8(sh[q * 2], sh[q * 2 + 1]);
    }
  }

  float hpf[8][4];  // f32 passthrough of previous h (acc fragment layout)

#define GPASS(SRC, ABUF, ACC)                       \
  __syncthreads();                                  \
  stage_w_rw(sW, (SRC), 128, 0, tid);               \
  __syncthreads();                                  \
  mfma_pass((ABUF), sW, (ACC), w, lane);

  // ---------------- GRU0: x=ns(sX), h=agg(sG) ----------------
  {
    f32x4 ar[8] = {}, az[8] = {}, ai[8] = {}, ah[8] = {};
    GPASS(g0W + 0 * 16384, sX, ar)
    GPASS(g0U + 0 * 16384, sG, ar)
    GPASS(g0W + 1 * 16384, sX, az)
    GPASS(g0U + 1 * 16384, sG, az)
    GPASS(g0W + 2 * 16384, sX, ai)
    GPASS(g0U + 2 * 16384, sG, ah)
    f32x4 h1[8];
#pragma unroll
    for (int nt = 0; nt < 8; ++nt) {
      int col = nt * 16 + (lane & 15);
      float brc = b0[col] + c0[col];
      float bzc = b0[128 + col] + c0[128 + col];
      float bi = b0[256 + col];
      float bc2 = c0[256 + col];
#pragma unroll
      for (int i = 0; i < 4; ++i) {
        int rloc = 16 * w + ((lane >> 4) * 4) + i;
        int row = r0 + rloc;
        int rowc = row < N ? row : N - 1;
        float hf = aggf[(size_t)rowc * 128 + col];
        float rg = 1.f / (1.f + __expf(-(ar[nt][i] + brc)));
        float zg = 1.f / (1.f + __expf(-(az[nt][i] + bzc)));
        float pre = ai[nt][i] + bi + rg * (ah[nt][i] + bc2);
        float ng = 2.f / (1.f + __expf(-2.f * pre)) - 1.f;
        float hv = (1.f - zg) * ng + zg * hf;
        h1[nt][i] = hv;
        hpf[nt][i] = hv;
      }
    }
    write_h_lds(sX, h1, w, lane);  // sX now holds h1 (bf16)
  }
  // ---------------- GRU1: x=agg(sG), h=h1(sX) ----------------
  {
    f32x4 ar[8] = {}, az[8] = {}, ai[8] = {}, ah[8] = {};
    GPASS(g1W + 0 * 16384, sG, ar)
    GPASS(g1U + 0 * 16384, sX, ar)
    GPASS(g1W + 1 * 16384, sG, az)
    GPASS(g1U + 1 * 16384, sX, az)
    GPASS(g1W + 2 * 16384, sG, ai)
    GPASS(g1U + 2 * 16384, sX, ah)
    f32x4 h2[8];
#pragma unroll
    for (int nt = 0; nt < 8; ++nt) {
      int col = nt * 16 + (lane & 15);
      float brc = b1[col] + c1[col];
      float bzc = b1[128 + col] + c1[128 + col];
      float bi = b1[256 + col];
      float bc2 = c1[256 + col];
#pragma unroll
      for (int i = 0; i < 4; ++i) {
        float rg = 1.f / (1.f + __expf(-(ar[nt][i] + brc)));
        float zg = 1.f / (1.f + __expf(-(az[nt][i] + bzc)));
        float pre = ai[nt][i] + bi + rg * (ah[nt][i] + bc2);
        float ng = 2.f / (1.f + __expf(-2.f * pre)) - 1.f;
        float hv = (1.f - zg) * ng + zg * hpf[nt][i];
        h2[nt][i] = hv;
        hpf[nt][i] = hv;
      }
    }
    write_h_lds(sG, h2, w, lane);  // sG now holds h2 (bf16)
  }
  // ---------------- GRU2: x=h1(sX), h=h2(sG) -> out ----------------
  {
    f32x4 ar[8] = {}, az[8] = {}, ai[8] = {}, ah[8] = {};
    GPASS(g2W + 0 * 16384, sX, ar)
    GPASS(g2U + 0 * 16384, sG, ar)
    GPASS(g2W + 1 * 16384, sX, az)
    GPASS(g2U + 1 * 16384, sG, az)
    GPASS(g2W + 2 * 16384, sX, ai)
    GPASS(g2U + 2 * 16384, sG, ah)
#pragma unroll
    for (int nt = 0; nt < 8; ++nt) {
      int col = nt * 16 + (lane & 15);
      float brc = b2[col] + c2[col];
      float bzc = b2[128 + col] + c2[128 + col];
      float bi = b2[256 + col];
      float bc2 = c2[256 + col];
#pragma unroll
      for (int i = 0; i < 4; ++i) {
        int rloc = 16 * w + ((lane >> 4) * 4) + i;
        int row = r0 + rloc;
        if (row < N) {
          float rg = 1.f / (1.f + __expf(-(ar[nt][i] + brc)));
          float zg = 1.f / (1.f + __expf(-(az[nt][i] + bzc)));
          float pre = ai[nt][i] + bi + rg * (ah[nt][i] + bc2);
          float ng = 2.f / (1.f + __expf(-2.f * pre)) - 1.f;
          out[(size_t)row * 128 + col] = (1.f - zg) * ng + zg * hpf[nt][i];
        }
      }
    }
  }
#undef GPASS
}

extern "C" void kernel_launch(void* const* d_in, const int* in_sizes, int n_in,
                              void* d_out, int out_size, void* d_ws,
                              size_t ws_size, hipStream_t stream) {
  const float* ns = (const float*)d_in[0];
  const float* ef = (const float*)d_in[1];
  const int* from_idx = (const int*)d_in[2];
  const int* to_idx = (const int*)d_in[3];
  const float* mW1 = (const float*)d_in[5];
  const float* mb1 = (const float*)d_in[6];
  const float* mW2 = (const float*)d_in[7];
  const float* mb2 = (const float*)d_in[8];
  const float* mW3 = (const float*)d_in[9];
  const float* mb3 = (const float*)d_in[10];
  const float* gW[3] = {(const float*)d_in[11], (const float*)d_in[15], (const float*)d_in[19]};
  const float* gU[3] = {(const float*)d_in[12], (const float*)d_in[16], (const float*)d_in[20]};
  const float* gb[3] = {(const float*)d_in[13], (const float*)d_in[17], (const float*)d_in[21]};
  const float* gc[3] = {(const float*)d_in[14], (const float*)d_in[18], (const float*)d_in[22]};

  const int N = in_sizes[0] / 128;
  const int E = in_sizes[1] / 128;

  // workspace layout
  char* base = (char*)d_ws;
  size_t cur = 0;
  auto alloc = [&](size_t bytes) {
    size_t p = cur;
    cur = (cur + bytes + 255) & ~(size_t)255;
    return (void*)(base + p);
  };
  float* aggf = (float*)alloc((size_t)N * 128 * 4);
  u16* Pa = (u16*)alloc((size_t)N * 128 * 2);
  u16* Pb = (u16*)alloc((size_t)N * 128 * 2);
  u16* Wt1 = (u16*)alloc(384 * 128 * 2);
  u16* Wt2 = (u16*)alloc(128 * 128 * 2);
  u16* Wt3 = (u16*)alloc(128 * 128 * 2);
  u16 *gWt[3], *gUt[3];
  for (int i = 0; i < 3; ++i) {
    gWt[i] = (u16*)alloc(384 * 128 * 2);
    gUt[i] = (u16*)alloc(384 * 128 * 2);
  }
  int* cnt = (int*)alloc((size_t)N * 4);
  int* off = (int*)alloc((size_t)(N + 1) * 4);
  int* cursor = (int*)alloc((size_t)N * 4);
  int* partial = (int*)alloc(256 * 4);
  int* pos0 = (int*)alloc((size_t)E * 4);
  int* pos1 = (int*)alloc((size_t)E * 4);
  u16* aggb = (u16*)alloc((size_t)N * 128 * 2);  // fallback accumulate buffer
  u16* msg = (u16*)alloc((size_t)2 * E * 128 * 2);
  bool csr_ok = (cur <= ws_size);

  // one-shot weight transpose (single kernel)
  {
    TransDesc td;
    const float* srcs[9] = {mW1, mW2, mW3, gW[0], gU[0], gW[1], gU[1], gW[2], gU[2]};
    u16* dsts[9] = {Wt1, Wt2, Wt3, gWt[0], gUt[0], gWt[1], gUt[1], gWt[2], gUt[2]};
    int Rs[9] = {384, 128, 128, 128, 128, 128, 128, 128, 128};
    int Cs[9] = {128, 128, 128, 384, 384, 384, 384, 384, 384};
    int acc = 0;
    for (int i = 0; i < 9; ++i) {
      td.src[i] = srcs[i];
      td.dst[i] = dsts[i];
      td.R[i] = Rs[i];
      td.C[i] = Cs[i];
      td.pre[i] = acc;
      acc += Rs[i] * Cs[i];
    }
    td.pre[9] = acc;
    transpose_all_kernel<<<(acc + 255) / 256, 256, 0, stream>>>(td);
  }

  node_partial_kernel<<<(N + 63) / 64, 256, 0, stream>>>(ns, Wt1, Pa, Pb, N);

  int ntiles = (E + 63) / 64;

  if (csr_ok) {
    hipMemsetAsync(cnt, 0, (size_t)N * 4, stream);
    count_kernel<<<(E + 255) / 256, 256, 0, stream>>>(from_idx, to_idx, cnt, E);
    int chunk = (N + 255) / 256;
    scan1_kernel<<<256, 256, 0, stream>>>(cnt, partial, N, chunk);
    scan2_kernel<<<1, 256, 0, stream>>>(partial, off, N);
    scan3_kernel<<<256, 256, 0, stream>>>(cnt, partial, off, cursor, N, chunk);
    pos_kernel<<<(E + 255) / 256, 256, 0, stream>>>(from_idx, to_idx, cursor,
                                                    pos0, pos1, E);
    int egrid = ntiles < 512 ? ntiles : 512;
    edge_fused_kernel<0><<<egrid, 512, 0, stream>>>(
        ef, from_idx, to_idx, Wt1, Wt2, Wt3, Pa, Pb, mb1, mb2, mb3, pos0, pos1,
        msg, E, ntiles);
    agg_csr_kernel<<<(N + 3) / 4, 256, 0, stream>>>(msg, off, aggf, N);
  } else {
    hipMemsetAsync(aggb, 0, (size_t)N * 128 * 2, stream);
    int egrid = ntiles < 512 ? ntiles : 512;
    edge_fused_kernel<1><<<egrid, 512, 0, stream>>>(
        ef, from_idx, to_idx, Wt1, Wt2, Wt3, Pa, Pb, mb1, mb2, mb3, pos0, pos1,
        aggb, E, ntiles);
    bf16_to_f32_kernel<<<(N * 16 + 255) / 256, 256, 0, stream>>>(aggb, aggf, N * 16);
  }

  int gblocks = (N + 63) / 64;
  gru3_kernel<<<gblocks, 256, 0, stream>>>(
      ns, aggf, gWt[0], gUt[0], gWt[1], gUt[1], gWt[2], gUt[2], gb[0], gc[0],
      gb[1], gc[1], gb[2], gc[2], (float*)d_out, N);
}